// Round 6
// baseline (4998.770 us; speedup 1.0000x reference)
//
#include <hip/hip_runtime.h>
#include <hip/hip_bf16.h>
#include <math.h>

// ---------------- problem constants ----------------
#define N_INSTR   16384
#define T_TOK     16
#define N_BLOCKS  512
#define MAX_BLK   64
#define HDIM      128
#define P_INSTR   32
#define P_GLOB    8
#define D_WORD    296     // 2*H + P_INSTR + P_GLOB
#define N_TOKENS  1024

#define CIB       32      // instructions per WG in char kernel

// per-parity h size: 2 dirs x 512 blocks x 128 units
#define HPAR      131072

__device__ __forceinline__ float sigf(float x) {
    return 1.0f / (1.0f + __expf(-x));
}
__device__ __forceinline__ float tanhf_s(float x) {
    float a = fabsf(x);
    float e = __expf(-2.0f * a);
    float t = (1.0f - e) / (1.0f + e);
    return copysignf(t, x);
}

// ---------------- weight packing ----------------
// Packed layout (float4 chunks over k): flat idx = ((k>>2)*NCOL + j)*4 + (k&3)
// charW4: NCOL=512, K=256 (kc 0..31: Wih, kc 32..63: Whh)
// wordW4p: NCOL=1024 (j<512 fwd, else bwd), K=296 (Wih only)
// wordW4h: NCOL=1024, K=128 (Whh only)
__global__ __launch_bounds__(256) void prep_pack(
    const float* __restrict__ cWihF, const float* __restrict__ cWhhF,
    const float* __restrict__ cWihB, const float* __restrict__ cWhhB,
    const float* __restrict__ wWihF, const float* __restrict__ wWihB,
    const float* __restrict__ wWhhF, const float* __restrict__ wWhhB,
    float* __restrict__ W4cf, float* __restrict__ W4cb,
    float* __restrict__ W4p,  float* __restrict__ W4h)
{
    int idx = blockIdx.x * 256 + threadIdx.x;
    if (idx < 131072) {                       // char fwd
        int kk = idx & 3, f = idx >> 2;
        int j = f & 511, k = ((f >> 9) << 2) + kk;
        W4cf[idx] = (k < 128) ? cWihF[j*128 + k] : cWhhF[j*128 + (k-128)];
    } else if (idx < 262144) {                // char bwd
        int id = idx - 131072;
        int kk = id & 3, f = id >> 2;
        int j = f & 511, k = ((f >> 9) << 2) + kk;
        W4cb[id] = (k < 128) ? cWihB[j*128 + k] : cWhhB[j*128 + (k-128)];
    } else if (idx < 262144 + 303104) {       // word input proj (K=296, N=1024)
        int id = idx - 262144;
        int kk = id & 3, f = id >> 2;
        int j = f & 1023, k = ((f >> 10) << 2) + kk;
        W4p[id] = (j < 512) ? wWihF[j*296 + k] : wWihB[(j-512)*296 + k];
    } else if (idx < 565248 + 131072) {       // word recurrent (K=128, N=1024)
        int id = idx - 565248;
        int kk = id & 3, f = id >> 2;
        int j = f & 1023, k = ((f >> 10) << 2) + kk;
        W4h[id] = (j < 512) ? wWhhF[j*128 + k] : wWhhB[(j-512)*128 + k];
    }
}

// ---------------- block scan: starts + instruction->block id ----------------
__global__ __launch_bounds__(512) void scan_kernel(
    const int* __restrict__ block_lens, int* __restrict__ starts, int* __restrict__ bid)
{
    __shared__ int s[N_BLOCKS];
    int t = threadIdx.x;
    int len = block_lens[t];
    s[t] = len;
    __syncthreads();
    for (int off = 1; off < N_BLOCKS; off <<= 1) {
        int v = (t >= off) ? s[t - off] : 0;
        __syncthreads();
        s[t] += v;
        __syncthreads();
    }
    int start = s[t] - len;
    starts[t] = start;
    for (int p = 0; p < len; ++p) bid[start + p] = t;
}

__global__ __launch_bounds__(256) void zero_kernel(float4* __restrict__ p, int n4)
{
    int i = blockIdx.x * 256 + threadIdx.x;
    if (i < n4) p[i] = make_float4(0.f, 0.f, 0.f, 0.f);
}

// ---------------- counting sort of instructions by token_len ----------------
// Output per-instruction results don't depend on WG grouping, so bucket-order
// nondeterminism (atomicAdd) is output-invariant.
__global__ __launch_bounds__(256) void sort_by_len(
    const int* __restrict__ token_lens, int* __restrict__ order)
{
    __shared__ int cnt[T_TOK + 1];
    __shared__ int base[T_TOK + 1];
    int tid = threadIdx.x;
    if (tid <= T_TOK) cnt[tid] = 0;
    __syncthreads();
    for (int i = tid; i < N_INSTR; i += 256) atomicAdd(&cnt[token_lens[i]], 1);
    __syncthreads();
    if (tid == 0) {
        int s = 0;
        for (int l = 0; l <= T_TOK; ++l) { base[l] = s; s += cnt[l]; }
    }
    __syncthreads();
    for (int i = tid; i < N_INSTR; i += 256) {
        int pos = atomicAdd(&base[token_lens[i]], 1);
        order[pos] = i;
    }
}

// ---------------- precompute E'[token] = emb[token] @ Wih^T (both dirs) ----------------
// EF4/EB4: [1024 tokens][128 units] float4 (gates 0..3), bias NOT included.
__global__ __launch_bounds__(256) void ex_pack(
    const float* __restrict__ emb,
    const float* __restrict__ W4cf, const float* __restrict__ W4cb,
    float* __restrict__ EF4, float* __restrict__ EB4)
{
    __shared__ float xe[128];
    int tk  = blockIdx.x;
    int tid = threadIdx.x;
    if (tid < 32) ((float4*)xe)[tid] = ((const float4*)(emb + tk * HDIM))[tid];
    __syncthreads();
    int u = tid & 127, dir = tid >> 7;
    const float4* W = (const float4*)(dir ? W4cb : W4cf);   // kc 0..31 = Wih part
    float a0 = 0.f, a1 = 0.f, a2 = 0.f, a3 = 0.f;
    for (int kc = 0; kc < 32; ++kc) {
        float4 x  = ((const float4*)xe)[kc];
        float4 w0 = W[kc*512 +   0 + u];
        float4 w1 = W[kc*512 + 128 + u];
        float4 w2 = W[kc*512 + 256 + u];
        float4 w3 = W[kc*512 + 384 + u];
        a0 = fmaf(w0.x,x.x,fmaf(w0.y,x.y,fmaf(w0.z,x.z,fmaf(w0.w,x.w,a0))));
        a1 = fmaf(w1.x,x.x,fmaf(w1.y,x.y,fmaf(w1.z,x.z,fmaf(w1.w,x.w,a1))));
        a2 = fmaf(w2.x,x.x,fmaf(w2.y,x.y,fmaf(w2.z,x.z,fmaf(w2.w,x.w,a2))));
        a3 = fmaf(w3.x,x.x,fmaf(w3.y,x.y,fmaf(w3.z,x.z,fmaf(w3.w,x.w,a3))));
    }
    float4 r = make_float4(a0, a1, a2, a3);
    ((float4*)(dir ? EB4 : EF4))[tk * 128 + u] = r;
}

// ---------------- char BiLSTM ----------------
// One WG = 32 instructions (length-sorted), 256 threads. Thread owns
// (unit u = tid&127, half -> 16 instructions), all 4 gates.
// Input projection comes from EF4/EB4 tables; only h@Whh^T (K=128) is
// recomputed per step. Loop runs to the WG's max token_len.
__global__ __launch_bounds__(256, 3) void char_lstm(
    const int* __restrict__ tokens, const int* __restrict__ token_lens,
    const int* __restrict__ order,
    const float* __restrict__ EF4, const float* __restrict__ EB4,
    const float* __restrict__ W4f, const float* __restrict__ W4b,
    const float* __restrict__ bf,  const float* __restrict__ bb,
    float* __restrict__ instr_h)
{
    __shared__ float hF[CIB][128];
    __shared__ float hB[CIB][128];
    __shared__ int   toks[CIB][T_TOK];
    __shared__ int   lens[CIB];
    __shared__ int   iid[CIB];
    __shared__ int   maxl_s;

    const int tid = threadIdx.x;
    const int i0  = blockIdx.x * CIB;

    if (tid == 0) maxl_s = 0;
    __syncthreads();
    if (tid < CIB) {
        int id = order[i0 + tid];
        iid[tid] = id;
        int l = token_lens[id];
        lens[tid] = l;
        atomicMax(&maxl_s, l);
    }
    __syncthreads();
    for (int idx = tid; idx < CIB * T_TOK; idx += 256)
        toks[idx >> 4][idx & 15] = tokens[iid[idx >> 4] * T_TOK + (idx & 15)];
    for (int idx = tid; idx < CIB * 128; idx += 256) {
        ((float*)hF)[idx] = 0.f;
        ((float*)hB)[idx] = 0.f;
    }
    __syncthreads();

    const int u    = tid & 127;
    const int half = tid >> 7;
    const int ib0  = half * 16;

    float bfr[4], bbr[4];
    #pragma unroll
    for (int g = 0; g < 4; ++g) { bfr[g] = bf[g*128 + u]; bbr[g] = bb[g*128 + u]; }

    float cF[16], cB[16];
    #pragma unroll
    for (int i = 0; i < 16; ++i) { cF[i] = 0.f; cB[i] = 0.f; }

    const float4* Wf = (const float4*)W4f + 32*512;   // Whh section (kc 32..63)
    const float4* Wb = (const float4*)W4b + 32*512;
    const float4* EF = (const float4*)EF4;
    const float4* EB = (const float4*)EB4;

    const int maxl = maxl_s;

    for (int t = 0; t < maxl; ++t) {
        // ---------- forward ----------
        {
            float acc[16][4];
            #pragma unroll
            for (int il = 0; il < 16; ++il) {
                float4 e = EF[toks[ib0 + il][t] * 128 + u];
                acc[il][0] = e.x; acc[il][1] = e.y; acc[il][2] = e.z; acc[il][3] = e.w;
            }
            for (int kc = 0; kc < 32; ++kc) {
                float4 w0 = Wf[kc*512 +   0 + u];
                float4 w1 = Wf[kc*512 + 128 + u];
                float4 w2 = Wf[kc*512 + 256 + u];
                float4 w3 = Wf[kc*512 + 384 + u];
                #pragma unroll
                for (int il = 0; il < 16; ++il) {
                    float4 x = *(const float4*)&hF[ib0 + il][kc*4];
                    acc[il][0] = fmaf(w0.x,x.x,fmaf(w0.y,x.y,fmaf(w0.z,x.z,fmaf(w0.w,x.w,acc[il][0]))));
                    acc[il][1] = fmaf(w1.x,x.x,fmaf(w1.y,x.y,fmaf(w1.z,x.z,fmaf(w1.w,x.w,acc[il][1]))));
                    acc[il][2] = fmaf(w2.x,x.x,fmaf(w2.y,x.y,fmaf(w2.z,x.z,fmaf(w2.w,x.w,acc[il][2]))));
                    acc[il][3] = fmaf(w3.x,x.x,fmaf(w3.y,x.y,fmaf(w3.z,x.z,fmaf(w3.w,x.w,acc[il][3]))));
                }
            }
            __syncthreads();     // all forward reads of hF done before writes
            #pragma unroll
            for (int il = 0; il < 16; ++il) {
                int i = ib0 + il;
                if (t < lens[i]) {
                    float gi = sigf   (acc[il][0] + bfr[0]);
                    float gf = sigf   (acc[il][1] + bfr[1]);
                    float gg = tanhf_s(acc[il][2] + bfr[2]);
                    float go = sigf   (acc[il][3] + bfr[3]);
                    float cn = gf * cF[il] + gi * gg;
                    cF[il] = cn;
                    hF[i][u] = go * tanhf_s(cn);
                }
            }
        }
        // ---------- backward ----------
        {
            float acc[16][4];
            #pragma unroll
            for (int il = 0; il < 16; ++il) {
                int i = ib0 + il;
                int tt = lens[i] - 1 - t;
                tt = tt < 0 ? 0 : tt;
                float4 e = EB[toks[i][tt] * 128 + u];
                acc[il][0] = e.x; acc[il][1] = e.y; acc[il][2] = e.z; acc[il][3] = e.w;
            }
            for (int kc = 0; kc < 32; ++kc) {
                float4 w0 = Wb[kc*512 +   0 + u];
                float4 w1 = Wb[kc*512 + 128 + u];
                float4 w2 = Wb[kc*512 + 256 + u];
                float4 w3 = Wb[kc*512 + 384 + u];
                #pragma unroll
                for (int il = 0; il < 16; ++il) {
                    float4 x = *(const float4*)&hB[ib0 + il][kc*4];
                    acc[il][0] = fmaf(w0.x,x.x,fmaf(w0.y,x.y,fmaf(w0.z,x.z,fmaf(w0.w,x.w,acc[il][0]))));
                    acc[il][1] = fmaf(w1.x,x.x,fmaf(w1.y,x.y,fmaf(w1.z,x.z,fmaf(w1.w,x.w,acc[il][1]))));
                    acc[il][2] = fmaf(w2.x,x.x,fmaf(w2.y,x.y,fmaf(w2.z,x.z,fmaf(w2.w,x.w,acc[il][2]))));
                    acc[il][3] = fmaf(w3.x,x.x,fmaf(w3.y,x.y,fmaf(w3.z,x.z,fmaf(w3.w,x.w,acc[il][3]))));
                }
            }
            __syncthreads();     // all backward reads of hB done before writes
            #pragma unroll
            for (int il = 0; il < 16; ++il) {
                int i = ib0 + il;
                if (t < lens[i]) {
                    float gi = sigf   (acc[il][0] + bbr[0]);
                    float gf = sigf   (acc[il][1] + bbr[1]);
                    float gg = tanhf_s(acc[il][2] + bbr[2]);
                    float go = sigf   (acc[il][3] + bbr[3]);
                    float cn = gf * cB[il] + gi * gg;
                    cB[il] = cn;
                    hB[i][u] = go * tanhf_s(cn);
                }
            }
        }
        __syncthreads();         // h writes visible before next step's k-loops
    }

    // write instr_h = [h_f | h_b] at ORIGINAL instruction ids
    for (int idx = tid; idx < CIB * 128; idx += 256) {
        int i = idx >> 7, uu = idx & 127;
        int id = iid[i];
        instr_h[id * 256 +       uu] = hF[i][uu];
        instr_h[id * 256 + 128 + uu] = hB[i][uu];
    }
}

// ---------------- gather word inputs xw[i][296] ----------------
__global__ __launch_bounds__(256) void xw_gather(
    const float* __restrict__ instr_h, const float* __restrict__ instr_params,
    const float* __restrict__ gparams, const int* __restrict__ bid,
    float* __restrict__ xw)
{
    int idx = blockIdx.x * 256 + threadIdx.x;       // float4 index
    if (idx >= N_INSTR * 74) return;
    int i = idx / 74, c = idx % 74;
    float4 v;
    if (c < 64)      v = ((const float4*)(instr_h + i*256))[c];
    else if (c < 72) v = ((const float4*)(instr_params + i*32))[c - 64];
    else             v = ((const float4*)(gparams + bid[i]*8))[c - 72];
    ((float4*)(xw + i*296))[c] = v;
}

// ---------------- word input projection P[i][1024] = xw @ [WihF|WihB]^T + b ----------------
__global__ __launch_bounds__(256) void word_proj(
    const float* __restrict__ xw, const float* __restrict__ W4p,
    const float* __restrict__ b_f, const float* __restrict__ b_b,
    float* __restrict__ P)
{
    __shared__ float xs[16][296];
    int tid = threadIdx.x;
    int rowTile = blockIdx.x >> 2;
    int colTile = blockIdx.x & 3;
    int i0 = rowTile * 16;

    for (int idx = tid; idx < 16 * 74; idx += 256) {
        int i = idx / 74, c = idx % 74;
        ((float4*)&xs[i][0])[c] = ((const float4*)(xw + (size_t)(i0 + i) * 296))[c];
    }
    __syncthreads();

    int j = colTile * 256 + tid;
    float acc[16];
    #pragma unroll
    for (int i = 0; i < 16; ++i) acc[i] = 0.f;
    const float4* W4 = (const float4*)W4p;
    for (int kc = 0; kc < 74; ++kc) {
        float4 w = W4[kc*1024 + j];
        #pragma unroll
        for (int i = 0; i < 16; ++i) {
            float4 x = ((const float4*)&xs[i][0])[kc];
            acc[i] = fmaf(w.x,x.x,fmaf(w.y,x.y,fmaf(w.z,x.z,fmaf(w.w,x.w,acc[i]))));
        }
    }
    float bias = (j < 512) ? b_f[j] : b_b[j - 512];
    for (int i = 0; i < 16; ++i)
        P[(size_t)(i0 + i) * 1024 + j] = acc[i] + bias;
}

// ---------------- word recurrent step ----------------
__global__ __launch_bounds__(256) void word_step(
    const float* __restrict__ W4h, const float* __restrict__ P,
    const int* __restrict__ starts, const int* __restrict__ block_lens,
    const float* __restrict__ hrd, float* __restrict__ hwr,
    float* __restrict__ cst, int t)
{
    __shared__ float hs[32][128];
    __shared__ int actflag;

    int bx = blockIdx.x;
    int bt = bx & 15, ut = (bx >> 4) & 3, d = bx >> 6;
    int tid = threadIdx.x;
    int b0 = bt * 32;

    const float* hbase = hrd + (size_t)(d * 512 + b0) * 128;
    for (int idx = tid; idx < 32 * 128 / 4; idx += 256)
        ((float4*)hs)[idx] = ((const float4*)hbase)[idx];
    if (tid == 0) actflag = 0;

    int u   = ut * 32 + (tid & 31);
    int bg  = tid >> 5;
    int lb0 = bg * 4;

    int blens[4], bsta[4], myact = 0;
    #pragma unroll
    for (int q = 0; q < 4; ++q) {
        int b = b0 + lb0 + q;
        blens[q] = block_lens[b];
        bsta[q]  = starts[b];
        myact |= (t < blens[q]) ? 1 : 0;
    }
    __syncthreads();
    if (myact) atomicOr(&actflag, 1);
    __syncthreads();

    float* hw = hwr + (size_t)(d * 512 + b0) * 128;
    if (!actflag) {  // whole tile inactive: copy-through our slice
        #pragma unroll
        for (int q = 0; q < 4; ++q) hw[(lb0 + q) * 128 + u] = hs[lb0 + q][u];
        return;
    }

    float acc[4][4];
    #pragma unroll
    for (int q = 0; q < 4; ++q)
        { acc[q][0]=0.f; acc[q][1]=0.f; acc[q][2]=0.f; acc[q][3]=0.f; }
    const float4* W4 = (const float4*)W4h;
    for (int kc = 0; kc < 32; ++kc) {
        float4 w0 = W4[kc*1024 + d*512 +   0 + u];
        float4 w1 = W4[kc*1024 + d*512 + 128 + u];
        float4 w2 = W4[kc*1024 + d*512 + 256 + u];
        float4 w3 = W4[kc*1024 + d*512 + 384 + u];
        #pragma unroll
        for (int q = 0; q < 4; ++q) {
            float4 h4 = *(const float4*)&hs[lb0 + q][kc*4];
            acc[q][0] = fmaf(w0.x,h4.x,fmaf(w0.y,h4.y,fmaf(w0.z,h4.z,fmaf(w0.w,h4.w,acc[q][0]))));
            acc[q][1] = fmaf(w1.x,h4.x,fmaf(w1.y,h4.y,fmaf(w1.z,h4.z,fmaf(w1.w,h4.w,acc[q][1]))));
            acc[q][2] = fmaf(w2.x,h4.x,fmaf(w2.y,h4.y,fmaf(w2.z,h4.z,fmaf(w2.w,h4.w,acc[q][2]))));
            acc[q][3] = fmaf(w3.x,h4.x,fmaf(w3.y,h4.y,fmaf(w3.z,h4.z,fmaf(w3.w,h4.w,acc[q][3]))));
        }
    }
    #pragma unroll
    for (int q = 0; q < 4; ++q) {
        int b = b0 + lb0 + q;
        int len = blens[q];
        float hold = hs[lb0 + q][u];
        if (t < len) {
            int rs = (d == 0) ? (bsta[q] + t) : (bsta[q] + len - 1 - t);
            const float* Prow = P + (size_t)rs * 1024 + d * 512;
            float g0 = acc[q][0] + Prow[  0 + u];
            float g1 = acc[q][1] + Prow[128 + u];
            float g2 = acc[q][2] + Prow[256 + u];
            float g3 = acc[q][3] + Prow[384 + u];
            float gi = sigf(g0), gf = sigf(g1), gg = tanhf_s(g2), go = sigf(g3);
            float* cp = cst + (size_t)(d * 512 + b) * 128 + u;
            float c  = *cp;
            float cn = gf * c + gi * gg;
            *cp = cn;
            hw[(lb0 + q) * 128 + u] = go * tanhf_s(cn);
        } else {
            hw[(lb0 + q) * 128 + u] = hold;
        }
    }
}

// ---------------- final linear ----------------
__global__ __launch_bounds__(256) void final_k(
    const float* __restrict__ hfinal, const float* __restrict__ gp,
    const float* __restrict__ fW, const float* __restrict__ fb,
    float* __restrict__ out)
{
    int tid = threadIdx.x;
    int w = tid >> 6, l = tid & 63;
    int b = blockIdx.x * 4 + w;
    const float* hf = hfinal + (size_t)(0 * 512 + b) * 128;
    const float* hb = hfinal + (size_t)(1 * 512 + b) * 128;
    float s = hf[l] * fW[l] + hf[l + 64] * fW[l + 64]
            + hb[l] * fW[128 + l] + hb[l + 64] * fW[192 + l];
    if (l < 8) s += gp[b * 8 + l] * fW[256 + l];
    #pragma unroll
    for (int off = 32; off > 0; off >>= 1) s += __shfl_down(s, off);
    if (l == 0) out[b] = s + fb[0];
}

// ---------------- launcher ----------------
extern "C" void kernel_launch(void* const* d_in, const int* in_sizes, int n_in,
                              void* d_out, int out_size, void* d_ws, size_t ws_size,
                              hipStream_t stream)
{
    const int*   tokens        = (const int*)  d_in[0];
    const int*   token_lens    = (const int*)  d_in[1];
    const int*   block_lens    = (const int*)  d_in[2];
    const float* instr_params  = (const float*)d_in[3];
    const float* global_params = (const float*)d_in[4];
    const float* emb           = (const float*)d_in[5];
    const float* cWihF = (const float*)d_in[6];
    const float* cWhhF = (const float*)d_in[7];
    const float* cbF   = (const float*)d_in[8];
    const float* cWihB = (const float*)d_in[9];
    const float* cWhhB = (const float*)d_in[10];
    const float* cbB   = (const float*)d_in[11];
    const float* wWihF = (const float*)d_in[12];
    const float* wWhhF = (const float*)d_in[13];
    const float* wbF   = (const float*)d_in[14];
    const float* wWihB = (const float*)d_in[15];
    const float* wWhhB = (const float*)d_in[16];
    const float* wbB   = (const float*)d_in[17];
    const float* fW    = (const float*)d_in[18];
    const float* fb    = (const float*)d_in[19];
    float* out = (float*)d_out;

    char* ws = (char*)d_ws;
    size_t off = 0;
    auto alloc_f = [&](size_t nfloats) { float* p = (float*)(ws + off); off += nfloats * 4; return p; };

    float* W4cf    = alloc_f(131072);
    float* W4cb    = alloc_f(131072);
    float* W4p     = alloc_f(303104);
    float* W4h     = alloc_f(131072);
    float* instr_h = alloc_f((size_t)N_INSTR * 256);
    float* xw      = alloc_f((size_t)N_INSTR * 296);
    float* P       = alloc_f((size_t)N_INSTR * 1024);
    float* hbuf    = alloc_f(2 * HPAR);             // 2 parities x (2 dirs x 512 x 128)
    float* cst     = alloc_f(2 * 512 * 128);        // contiguous after hbuf
    float* EF4     = alloc_f((size_t)N_TOKENS * 128 * 4);
    float* EB4     = alloc_f((size_t)N_TOKENS * 128 * 4);
    int*   starts  = (int*)(ws + off); off += 512 * 4;
    int*   bid     = (int*)(ws + off); off += N_INSTR * 4;
    int*   order   = (int*)(ws + off); off += N_INSTR * 4;

    prep_pack<<<2720, 256, 0, stream>>>(cWihF, cWhhF, cWihB, cWhhB,
                                        wWihF, wWihB, wWhhF, wWhhB,
                                        W4cf, W4cb, W4p, W4h);
    // zero hbuf (both parities) + cstate: 262144 + 131072 = 393216 floats = 98304 float4
    zero_kernel<<<384, 256, 0, stream>>>((float4*)hbuf, 98304);
    scan_kernel<<<1, 512, 0, stream>>>(block_lens, starts, bid);
    sort_by_len<<<1, 256, 0, stream>>>(token_lens, order);
    ex_pack<<<N_TOKENS, 256, 0, stream>>>(emb, W4cf, W4cb, EF4, EB4);

    char_lstm<<<N_INSTR / CIB, 256, 0, stream>>>(tokens, token_lens, order,
                                                 EF4, EB4, W4cf, W4cb,
                                                 cbF, cbB, instr_h);
    xw_gather<<<4736, 256, 0, stream>>>(instr_h, instr_params, global_params, bid, xw);
    word_proj<<<4096, 256, 0, stream>>>(xw, W4p, wbF, wbB, P);

    for (int t = 0; t < MAX_BLK; ++t) {
        const float* hrd = hbuf + (size_t)(t & 1) * HPAR;
        float*       hwr = hbuf + (size_t)((t + 1) & 1) * HPAR;
        word_step<<<128, 256, 0, stream>>>(W4h, P, starts, block_lens, hrd, hwr, cst, t);
    }
    // final h is in parity 0 after t=63
    final_k<<<128, 256, 0, stream>>>(hbuf, global_params, fW, fb, out);
}

// Round 8
// 1695.527 us; speedup vs baseline: 2.9482x; 2.9482x over previous
//
#include <hip/hip_runtime.h>
#include <hip/hip_bf16.h>
#include <math.h>

// ---------------- problem constants ----------------
#define N_INSTR   16384
#define T_TOK     16
#define N_BLOCKS  512
#define MAX_BLK   64
#define HDIM      128
#define P_INSTR   32
#define P_GLOB    8
#define D_WORD    296     // 2*H + P_INSTR + P_GLOB
#define N_TOKENS  1024

#define CIB       32      // instructions per WG in char kernel

// per-parity h size: 2 dirs x 512 blocks x 128 units
#define HPAR      131072

__device__ __forceinline__ float sigf(float x) {
    return 1.0f / (1.0f + __expf(-x));
}
__device__ __forceinline__ float tanhf_s(float x) {
    float a = fabsf(x);
    float e = __expf(-2.0f * a);
    float t = (1.0f - e) / (1.0f + e);
    return copysignf(t, x);
}

// ---------------- weight packing ----------------
// Packed layout (float4 chunks over k): flat idx = ((k>>2)*NCOL + j)*4 + (k&3)
// charW4: NCOL=512, K=256 (kc 0..31: Wih, kc 32..63: Whh)
// wordW4p: NCOL=1024 (j<512 fwd, else bwd), K=296 (Wih only)
// wordW4h: NCOL=1024, K=128 (Whh only)
__global__ __launch_bounds__(256) void prep_pack(
    const float* __restrict__ cWihF, const float* __restrict__ cWhhF,
    const float* __restrict__ cWihB, const float* __restrict__ cWhhB,
    const float* __restrict__ wWihF, const float* __restrict__ wWihB,
    const float* __restrict__ wWhhF, const float* __restrict__ wWhhB,
    float* __restrict__ W4cf, float* __restrict__ W4cb,
    float* __restrict__ W4p,  float* __restrict__ W4h)
{
    int idx = blockIdx.x * 256 + threadIdx.x;
    if (idx < 131072) {                       // char fwd
        int kk = idx & 3, f = idx >> 2;
        int j = f & 511, k = ((f >> 9) << 2) + kk;
        W4cf[idx] = (k < 128) ? cWihF[j*128 + k] : cWhhF[j*128 + (k-128)];
    } else if (idx < 262144) {                // char bwd
        int id = idx - 131072;
        int kk = id & 3, f = id >> 2;
        int j = f & 511, k = ((f >> 9) << 2) + kk;
        W4cb[id] = (k < 128) ? cWihB[j*128 + k] : cWhhB[j*128 + (k-128)];
    } else if (idx < 262144 + 303104) {       // word input proj (K=296, N=1024)
        int id = idx - 262144;
        int kk = id & 3, f = id >> 2;
        int j = f & 1023, k = ((f >> 10) << 2) + kk;
        W4p[id] = (j < 512) ? wWihF[j*296 + k] : wWihB[(j-512)*296 + k];
    } else if (idx < 565248 + 131072) {       // word recurrent (K=128, N=1024)
        int id = idx - 565248;
        int kk = id & 3, f = id >> 2;
        int j = f & 1023, k = ((f >> 10) << 2) + kk;
        W4h[id] = (j < 512) ? wWhhF[j*128 + k] : wWhhB[(j-512)*128 + k];
    }
}

// ---------------- block scan: starts + instruction->block id ----------------
__global__ __launch_bounds__(512) void scan_kernel(
    const int* __restrict__ block_lens, int* __restrict__ starts, int* __restrict__ bid)
{
    __shared__ int s[N_BLOCKS];
    int t = threadIdx.x;
    int len = block_lens[t];
    s[t] = len;
    __syncthreads();
    for (int off = 1; off < N_BLOCKS; off <<= 1) {
        int v = (t >= off) ? s[t - off] : 0;
        __syncthreads();
        s[t] += v;
        __syncthreads();
    }
    int start = s[t] - len;
    starts[t] = start;
    for (int p = 0; p < len; ++p) bid[start + p] = t;
}

__global__ __launch_bounds__(256) void zero_kernel(float4* __restrict__ p, int n4)
{
    int i = blockIdx.x * 256 + threadIdx.x;
    if (i < n4) p[i] = make_float4(0.f, 0.f, 0.f, 0.f);
}

// ---------------- counting sort of instructions by token_len ----------------
__global__ __launch_bounds__(256) void sort_by_len(
    const int* __restrict__ token_lens, int* __restrict__ order)
{
    __shared__ int cnt[T_TOK + 1];
    __shared__ int base[T_TOK + 1];
    int tid = threadIdx.x;
    if (tid <= T_TOK) cnt[tid] = 0;
    __syncthreads();
    for (int i = tid; i < N_INSTR; i += 256) atomicAdd(&cnt[token_lens[i]], 1);
    __syncthreads();
    if (tid == 0) {
        int s = 0;
        for (int l = 0; l <= T_TOK; ++l) { base[l] = s; s += cnt[l]; }
    }
    __syncthreads();
    for (int i = tid; i < N_INSTR; i += 256) {
        int pos = atomicAdd(&base[token_lens[i]], 1);
        order[pos] = i;
    }
}

// ---------------- precompute E'[token] = emb[token] @ Wih^T (both dirs) ----------------
// EF4/EB4: [1024 tokens][128 units] float4 (gates 0..3), bias NOT included.
__global__ __launch_bounds__(256) void ex_pack(
    const float* __restrict__ emb,
    const float* __restrict__ W4cf, const float* __restrict__ W4cb,
    float* __restrict__ EF4, float* __restrict__ EB4)
{
    __shared__ float xe[128];
    int tk  = blockIdx.x;
    int tid = threadIdx.x;
    if (tid < 32) ((float4*)xe)[tid] = ((const float4*)(emb + tk * HDIM))[tid];
    __syncthreads();
    int u = tid & 127, dir = tid >> 7;
    const float4* W = (const float4*)(dir ? W4cb : W4cf);   // kc 0..31 = Wih part
    float a0 = 0.f, a1 = 0.f, a2 = 0.f, a3 = 0.f;
    for (int kc = 0; kc < 32; ++kc) {
        float4 x  = ((const float4*)xe)[kc];
        float4 w0 = W[kc*512 +   0 + u];
        float4 w1 = W[kc*512 + 128 + u];
        float4 w2 = W[kc*512 + 256 + u];
        float4 w3 = W[kc*512 + 384 + u];
        a0 = fmaf(w0.x,x.x,fmaf(w0.y,x.y,fmaf(w0.z,x.z,fmaf(w0.w,x.w,a0))));
        a1 = fmaf(w1.x,x.x,fmaf(w1.y,x.y,fmaf(w1.z,x.z,fmaf(w1.w,x.w,a1))));
        a2 = fmaf(w2.x,x.x,fmaf(w2.y,x.y,fmaf(w2.z,x.z,fmaf(w2.w,x.w,a2))));
        a3 = fmaf(w3.x,x.x,fmaf(w3.y,x.y,fmaf(w3.z,x.z,fmaf(w3.w,x.w,a3))));
    }
    float4 r = make_float4(a0, a1, a2, a3);
    ((float4*)(dir ? EB4 : EF4))[tk * 128 + u] = r;
}

// ---------------- char BiLSTM ----------------
// One WG = 32 instructions (length-sorted), 256 threads. Thread owns
// (unit u = tid&127, half -> 16 instructions), all 4 gates.
// Input projection comes from EF4/EB4 tables; only h@Whh^T (K=128) is
// recomputed per step. Loop runs to the WG's max token_len.
// launch_bounds (256,2): (256,3) in r6 drove regalloc to 84 VGPR and
// spilled acc[16][4] -> 10 GB/dispatch scratch traffic, 2.3x slower.
__global__ __launch_bounds__(256, 2) void char_lstm(
    const int* __restrict__ tokens, const int* __restrict__ token_lens,
    const int* __restrict__ order,
    const float* __restrict__ EF4, const float* __restrict__ EB4,
    const float* __restrict__ W4f, const float* __restrict__ W4b,
    const float* __restrict__ bf,  const float* __restrict__ bb,
    float* __restrict__ instr_h)
{
    __shared__ float hF[CIB][128];
    __shared__ float hB[CIB][128];
    __shared__ int   toks[CIB][T_TOK];
    __shared__ int   lens[CIB];
    __shared__ int   iid[CIB];
    __shared__ int   maxl_s;

    const int tid = threadIdx.x;
    const int i0  = blockIdx.x * CIB;

    if (tid == 0) maxl_s = 0;
    __syncthreads();
    if (tid < CIB) {
        int id = order[i0 + tid];
        iid[tid] = id;
        int l = token_lens[id];
        lens[tid] = l;
        atomicMax(&maxl_s, l);
    }
    __syncthreads();
    for (int idx = tid; idx < CIB * T_TOK; idx += 256)
        toks[idx >> 4][idx & 15] = tokens[iid[idx >> 4] * T_TOK + (idx & 15)];
    for (int idx = tid; idx < CIB * 128; idx += 256) {
        ((float*)hF)[idx] = 0.f;
        ((float*)hB)[idx] = 0.f;
    }
    __syncthreads();

    const int u    = tid & 127;
    const int half = tid >> 7;
    const int ib0  = half * 16;

    float bfr[4], bbr[4];
    #pragma unroll
    for (int g = 0; g < 4; ++g) { bfr[g] = bf[g*128 + u]; bbr[g] = bb[g*128 + u]; }

    float cF[16], cB[16];
    #pragma unroll
    for (int i = 0; i < 16; ++i) { cF[i] = 0.f; cB[i] = 0.f; }

    const float4* Wf = (const float4*)W4f + 32*512;   // Whh section (kc 32..63)
    const float4* Wb = (const float4*)W4b + 32*512;
    const float4* EF = (const float4*)EF4;
    const float4* EB = (const float4*)EB4;

    const int maxl = maxl_s;

    for (int t = 0; t < maxl; ++t) {
        // ---------- forward ----------
        {
            float acc[16][4];
            #pragma unroll
            for (int il = 0; il < 16; ++il) {
                float4 e = EF[toks[ib0 + il][t] * 128 + u];
                acc[il][0] = e.x; acc[il][1] = e.y; acc[il][2] = e.z; acc[il][3] = e.w;
            }
            for (int kc = 0; kc < 32; ++kc) {
                float4 w0 = Wf[kc*512 +   0 + u];
                float4 w1 = Wf[kc*512 + 128 + u];
                float4 w2 = Wf[kc*512 + 256 + u];
                float4 w3 = Wf[kc*512 + 384 + u];
                #pragma unroll
                for (int il = 0; il < 16; ++il) {
                    float4 x = *(const float4*)&hF[ib0 + il][kc*4];
                    acc[il][0] = fmaf(w0.x,x.x,fmaf(w0.y,x.y,fmaf(w0.z,x.z,fmaf(w0.w,x.w,acc[il][0]))));
                    acc[il][1] = fmaf(w1.x,x.x,fmaf(w1.y,x.y,fmaf(w1.z,x.z,fmaf(w1.w,x.w,acc[il][1]))));
                    acc[il][2] = fmaf(w2.x,x.x,fmaf(w2.y,x.y,fmaf(w2.z,x.z,fmaf(w2.w,x.w,acc[il][2]))));
                    acc[il][3] = fmaf(w3.x,x.x,fmaf(w3.y,x.y,fmaf(w3.z,x.z,fmaf(w3.w,x.w,acc[il][3]))));
                }
            }
            __syncthreads();     // all forward reads of hF done before writes
            #pragma unroll
            for (int il = 0; il < 16; ++il) {
                int i = ib0 + il;
                if (t < lens[i]) {
                    float gi = sigf   (acc[il][0] + bfr[0]);
                    float gf = sigf   (acc[il][1] + bfr[1]);
                    float gg = tanhf_s(acc[il][2] + bfr[2]);
                    float go = sigf   (acc[il][3] + bfr[3]);
                    float cn = gf * cF[il] + gi * gg;
                    cF[il] = cn;
                    hF[i][u] = go * tanhf_s(cn);
                }
            }
        }
        // ---------- backward ----------
        {
            float acc[16][4];
            #pragma unroll
            for (int il = 0; il < 16; ++il) {
                int i = ib0 + il;
                int tt = lens[i] - 1 - t;
                tt = tt < 0 ? 0 : tt;
                float4 e = EB[toks[i][tt] * 128 + u];
                acc[il][0] = e.x; acc[il][1] = e.y; acc[il][2] = e.z; acc[il][3] = e.w;
            }
            for (int kc = 0; kc < 32; ++kc) {
                float4 w0 = Wb[kc*512 +   0 + u];
                float4 w1 = Wb[kc*512 + 128 + u];
                float4 w2 = Wb[kc*512 + 256 + u];
                float4 w3 = Wb[kc*512 + 384 + u];
                #pragma unroll
                for (int il = 0; il < 16; ++il) {
                    float4 x = *(const float4*)&hB[ib0 + il][kc*4];
                    acc[il][0] = fmaf(w0.x,x.x,fmaf(w0.y,x.y,fmaf(w0.z,x.z,fmaf(w0.w,x.w,acc[il][0]))));
                    acc[il][1] = fmaf(w1.x,x.x,fmaf(w1.y,x.y,fmaf(w1.z,x.z,fmaf(w1.w,x.w,acc[il][1]))));
                    acc[il][2] = fmaf(w2.x,x.x,fmaf(w2.y,x.y,fmaf(w2.z,x.z,fmaf(w2.w,x.w,acc[il][2]))));
                    acc[il][3] = fmaf(w3.x,x.x,fmaf(w3.y,x.y,fmaf(w3.z,x.z,fmaf(w3.w,x.w,acc[il][3]))));
                }
            }
            __syncthreads();     // all backward reads of hB done before writes
            #pragma unroll
            for (int il = 0; il < 16; ++il) {
                int i = ib0 + il;
                if (t < lens[i]) {
                    float gi = sigf   (acc[il][0] + bbr[0]);
                    float gf = sigf   (acc[il][1] + bbr[1]);
                    float gg = tanhf_s(acc[il][2] + bbr[2]);
                    float go = sigf   (acc[il][3] + bbr[3]);
                    float cn = gf * cB[il] + gi * gg;
                    cB[il] = cn;
                    hB[i][u] = go * tanhf_s(cn);
                }
            }
        }
        __syncthreads();         // h writes visible before next step's k-loops
    }

    // write instr_h = [h_f | h_b] at ORIGINAL instruction ids
    for (int idx = tid; idx < CIB * 128; idx += 256) {
        int i = idx >> 7, uu = idx & 127;
        int id = iid[i];
        instr_h[id * 256 +       uu] = hF[i][uu];
        instr_h[id * 256 + 128 + uu] = hB[i][uu];
    }
}

// ---------------- gather word inputs xw[i][296] ----------------
__global__ __launch_bounds__(256) void xw_gather(
    const float* __restrict__ instr_h, const float* __restrict__ instr_params,
    const float* __restrict__ gparams, const int* __restrict__ bid,
    float* __restrict__ xw)
{
    int idx = blockIdx.x * 256 + threadIdx.x;       // float4 index
    if (idx >= N_INSTR * 74) return;
    int i = idx / 74, c = idx % 74;
    float4 v;
    if (c < 64)      v = ((const float4*)(instr_h + i*256))[c];
    else if (c < 72) v = ((const float4*)(instr_params + i*32))[c - 64];
    else             v = ((const float4*)(gparams + bid[i]*8))[c - 72];
    ((float4*)(xw + i*296))[c] = v;
}

// ---------------- word input projection P[i][1024] = xw @ [WihF|WihB]^T + b ----------------
__global__ __launch_bounds__(256) void word_proj(
    const float* __restrict__ xw, const float* __restrict__ W4p,
    const float* __restrict__ b_f, const float* __restrict__ b_b,
    float* __restrict__ P)
{
    __shared__ float xs[16][296];
    int tid = threadIdx.x;
    int rowTile = blockIdx.x >> 2;
    int colTile = blockIdx.x & 3;
    int i0 = rowTile * 16;

    for (int idx = tid; idx < 16 * 74; idx += 256) {
        int i = idx / 74, c = idx % 74;
        ((float4*)&xs[i][0])[c] = ((const float4*)(xw + (size_t)(i0 + i) * 296))[c];
    }
    __syncthreads();

    int j = colTile * 256 + tid;
    float acc[16];
    #pragma unroll
    for (int i = 0; i < 16; ++i) acc[i] = 0.f;
    const float4* W4 = (const float4*)W4p;
    for (int kc = 0; kc < 74; ++kc) {
        float4 w = W4[kc*1024 + j];
        #pragma unroll
        for (int i = 0; i < 16; ++i) {
            float4 x = ((const float4*)&xs[i][0])[kc];
            acc[i] = fmaf(w.x,x.x,fmaf(w.y,x.y,fmaf(w.z,x.z,fmaf(w.w,x.w,acc[i]))));
        }
    }
    float bias = (j < 512) ? b_f[j] : b_b[j - 512];
    for (int i = 0; i < 16; ++i)
        P[(size_t)(i0 + i) * 1024 + j] = acc[i] + bias;
}

// ---------------- word recurrent step ----------------
__global__ __launch_bounds__(256) void word_step(
    const float* __restrict__ W4h, const float* __restrict__ P,
    const int* __restrict__ starts, const int* __restrict__ block_lens,
    const float* __restrict__ hrd, float* __restrict__ hwr,
    float* __restrict__ cst, int t)
{
    __shared__ float hs[32][128];
    __shared__ int actflag;

    int bx = blockIdx.x;
    int bt = bx & 15, ut = (bx >> 4) & 3, d = bx >> 6;
    int tid = threadIdx.x;
    int b0 = bt * 32;

    const float* hbase = hrd + (size_t)(d * 512 + b0) * 128;
    for (int idx = tid; idx < 32 * 128 / 4; idx += 256)
        ((float4*)hs)[idx] = ((const float4*)hbase)[idx];
    if (tid == 0) actflag = 0;

    int u   = ut * 32 + (tid & 31);
    int bg  = tid >> 5;
    int lb0 = bg * 4;

    int blens[4], bsta[4], myact = 0;
    #pragma unroll
    for (int q = 0; q < 4; ++q) {
        int b = b0 + lb0 + q;
        blens[q] = block_lens[b];
        bsta[q]  = starts[b];
        myact |= (t < blens[q]) ? 1 : 0;
    }
    __syncthreads();
    if (myact) atomicOr(&actflag, 1);
    __syncthreads();

    float* hw = hwr + (size_t)(d * 512 + b0) * 128;
    if (!actflag) {  // whole tile inactive: copy-through our slice
        #pragma unroll
        for (int q = 0; q < 4; ++q) hw[(lb0 + q) * 128 + u] = hs[lb0 + q][u];
        return;
    }

    float acc[4][4];
    #pragma unroll
    for (int q = 0; q < 4; ++q)
        { acc[q][0]=0.f; acc[q][1]=0.f; acc[q][2]=0.f; acc[q][3]=0.f; }
    const float4* W4 = (const float4*)W4h;
    for (int kc = 0; kc < 32; ++kc) {
        float4 w0 = W4[kc*1024 + d*512 +   0 + u];
        float4 w1 = W4[kc*1024 + d*512 + 128 + u];
        float4 w2 = W4[kc*1024 + d*512 + 256 + u];
        float4 w3 = W4[kc*1024 + d*512 + 384 + u];
        #pragma unroll
        for (int q = 0; q < 4; ++q) {
            float4 h4 = *(const float4*)&hs[lb0 + q][kc*4];
            acc[q][0] = fmaf(w0.x,h4.x,fmaf(w0.y,h4.y,fmaf(w0.z,h4.z,fmaf(w0.w,h4.w,acc[q][0]))));
            acc[q][1] = fmaf(w1.x,h4.x,fmaf(w1.y,h4.y,fmaf(w1.z,h4.z,fmaf(w1.w,h4.w,acc[q][1]))));
            acc[q][2] = fmaf(w2.x,h4.x,fmaf(w2.y,h4.y,fmaf(w2.z,h4.z,fmaf(w2.w,h4.w,acc[q][2]))));
            acc[q][3] = fmaf(w3.x,h4.x,fmaf(w3.y,h4.y,fmaf(w3.z,h4.z,fmaf(w3.w,h4.w,acc[q][3]))));
        }
    }
    #pragma unroll
    for (int q = 0; q < 4; ++q) {
        int b = b0 + lb0 + q;
        int len = blens[q];
        float hold = hs[lb0 + q][u];
        if (t < len) {
            int rs = (d == 0) ? (bsta[q] + t) : (bsta[q] + len - 1 - t);
            const float* Prow = P + (size_t)rs * 1024 + d * 512;
            float g0 = acc[q][0] + Prow[  0 + u];
            float g1 = acc[q][1] + Prow[128 + u];
            float g2 = acc[q][2] + Prow[256 + u];
            float g3 = acc[q][3] + Prow[384 + u];
            float gi = sigf(g0), gf = sigf(g1), gg = tanhf_s(g2), go = sigf(g3);
            float* cp = cst + (size_t)(d * 512 + b) * 128 + u;
            float c  = *cp;
            float cn = gf * c + gi * gg;
            *cp = cn;
            hw[(lb0 + q) * 128 + u] = go * tanhf_s(cn);
        } else {
            hw[(lb0 + q) * 128 + u] = hold;
        }
    }
}

// ---------------- final linear ----------------
__global__ __launch_bounds__(256) void final_k(
    const float* __restrict__ hfinal, const float* __restrict__ gp,
    const float* __restrict__ fW, const float* __restrict__ fb,
    float* __restrict__ out)
{
    int tid = threadIdx.x;
    int w = tid >> 6, l = tid & 63;
    int b = blockIdx.x * 4 + w;
    const float* hf = hfinal + (size_t)(0 * 512 + b) * 128;
    const float* hb = hfinal + (size_t)(1 * 512 + b) * 128;
    float s = hf[l] * fW[l] + hf[l + 64] * fW[l + 64]
            + hb[l] * fW[128 + l] + hb[l + 64] * fW[192 + l];
    if (l < 8) s += gp[b * 8 + l] * fW[256 + l];
    #pragma unroll
    for (int off = 32; off > 0; off >>= 1) s += __shfl_down(s, off);
    if (l == 0) out[b] = s + fb[0];
}

// ---------------- launcher ----------------
extern "C" void kernel_launch(void* const* d_in, const int* in_sizes, int n_in,
                              void* d_out, int out_size, void* d_ws, size_t ws_size,
                              hipStream_t stream)
{
    const int*   tokens        = (const int*)  d_in[0];
    const int*   token_lens    = (const int*)  d_in[1];
    const int*   block_lens    = (const int*)  d_in[2];
    const float* instr_params  = (const float*)d_in[3];
    const float* global_params = (const float*)d_in[4];
    const float* emb           = (const float*)d_in[5];
    const float* cWihF = (const float*)d_in[6];
    const float* cWhhF = (const float*)d_in[7];
    const float* cbF   = (const float*)d_in[8];
    const float* cWihB = (const float*)d_in[9];
    const float* cWhhB = (const float*)d_in[10];
    const float* cbB   = (const float*)d_in[11];
    const float* wWihF = (const float*)d_in[12];
    const float* wWhhF = (const float*)d_in[13];
    const float* wbF   = (const float*)d_in[14];
    const float* wWihB = (const float*)d_in[15];
    const float* wWhhB = (const float*)d_in[16];
    const float* wbB   = (const float*)d_in[17];
    const float* fW    = (const float*)d_in[18];
    const float* fb    = (const float*)d_in[19];
    float* out = (float*)d_out;

    char* ws = (char*)d_ws;
    size_t off = 0;
    auto alloc_f = [&](size_t nfloats) { float* p = (float*)(ws + off); off += nfloats * 4; return p; };

    float* W4cf    = alloc_f(131072);
    float* W4cb    = alloc_f(131072);
    float* W4p     = alloc_f(303104);
    float* W4h     = alloc_f(131072);
    float* instr_h = alloc_f((size_t)N_INSTR * 256);
    float* xw      = alloc_f((size_t)N_INSTR * 296);
    float* P       = alloc_f((size_t)N_INSTR * 1024);
    float* hbuf    = alloc_f(2 * HPAR);             // 2 parities x (2 dirs x 512 x 128)
    float* cst     = alloc_f(2 * 512 * 128);        // contiguous after hbuf
    float* EF4     = alloc_f((size_t)N_TOKENS * 128 * 4);
    float* EB4     = alloc_f((size_t)N_TOKENS * 128 * 4);
    int*   starts  = (int*)(ws + off); off += 512 * 4;
    int*   bid     = (int*)(ws + off); off += N_INSTR * 4;
    int*   order   = (int*)(ws + off); off += N_INSTR * 4;

    prep_pack<<<2720, 256, 0, stream>>>(cWihF, cWhhF, cWihB, cWhhB,
                                        wWihF, wWihB, wWhhF, wWhhB,
                                        W4cf, W4cb, W4p, W4h);
    // zero hbuf (both parities) + cstate: 262144 + 131072 = 393216 floats = 98304 float4
    zero_kernel<<<384, 256, 0, stream>>>((float4*)hbuf, 98304);
    scan_kernel<<<1, 512, 0, stream>>>(block_lens, starts, bid);
    sort_by_len<<<1, 256, 0, stream>>>(token_lens, order);
    ex_pack<<<N_TOKENS, 256, 0, stream>>>(emb, W4cf, W4cb, EF4, EB4);

    char_lstm<<<N_INSTR / CIB, 256, 0, stream>>>(tokens, token_lens, order,
                                                 EF4, EB4, W4cf, W4cb,
                                                 cbF, cbB, instr_h);
    xw_gather<<<4736, 256, 0, stream>>>(instr_h, instr_params, global_params, bid, xw);
    word_proj<<<4096, 256, 0, stream>>>(xw, W4p, wbF, wbB, P);

    for (int t = 0; t < MAX_BLK; ++t) {
        const float* hrd = hbuf + (size_t)(t & 1) * HPAR;
        float*       hwr = hbuf + (size_t)((t + 1) & 1) * HPAR;
        word_step<<<128, 256, 0, stream>>>(W4h, P, starts, block_lens, hrd, hwr, cst, t);
    }
    // final h is in parity 0 after t=63
    final_k<<<128, 256, 0, stream>>>(hbuf, global_params, fW, fb, out);
}

// Round 10
// 1433.496 us; speedup vs baseline: 3.4871x; 1.1828x over previous
//
#include <hip/hip_runtime.h>
#include <hip/hip_bf16.h>
#include <math.h>

// ---------------- problem constants ----------------
#define N_INSTR   16384
#define T_TOK     16
#define N_BLOCKS  512
#define MAX_BLK   64
#define HDIM      128
#define P_INSTR   32
#define P_GLOB    8
#define D_WORD    296     // 2*H + P_INSTR + P_GLOB
#define N_TOKENS  1024

#define CIB       16      // instructions per WG in char kernel (r8: 32 -> grid 512 = 2 WG/CU, grid-limited occupancy 13%)

__device__ __forceinline__ float sigf(float x) {
    return 1.0f / (1.0f + __expf(-x));
}
__device__ __forceinline__ float tanhf_s(float x) {
    float a = fabsf(x);
    float e = __expf(-2.0f * a);
    float t = (1.0f - e) / (1.0f + e);
    return copysignf(t, x);
}

// ---------------- weight packing ----------------
// Packed layout (float4 chunks over k): flat idx = ((k>>2)*NCOL + j)*4 + (k&3)
// charW4: NCOL=512, K=256 (kc 0..31: Wih, kc 32..63: Whh)
// wordW4p: NCOL=1024 (j<512 fwd, else bwd), K=296 (Wih only)
// wordW4h: NCOL=1024, K=128 (Whh only)
__global__ __launch_bounds__(256) void prep_pack(
    const float* __restrict__ cWihF, const float* __restrict__ cWhhF,
    const float* __restrict__ cWihB, const float* __restrict__ cWhhB,
    const float* __restrict__ wWihF, const float* __restrict__ wWihB,
    const float* __restrict__ wWhhF, const float* __restrict__ wWhhB,
    float* __restrict__ W4cf, float* __restrict__ W4cb,
    float* __restrict__ W4p,  float* __restrict__ W4h)
{
    int idx = blockIdx.x * 256 + threadIdx.x;
    if (idx < 131072) {                       // char fwd
        int kk = idx & 3, f = idx >> 2;
        int j = f & 511, k = ((f >> 9) << 2) + kk;
        W4cf[idx] = (k < 128) ? cWihF[j*128 + k] : cWhhF[j*128 + (k-128)];
    } else if (idx < 262144) {                // char bwd
        int id = idx - 131072;
        int kk = id & 3, f = id >> 2;
        int j = f & 511, k = ((f >> 9) << 2) + kk;
        W4cb[id] = (k < 128) ? cWihB[j*128 + k] : cWhhB[j*128 + (k-128)];
    } else if (idx < 262144 + 303104) {       // word input proj (K=296, N=1024)
        int id = idx - 262144;
        int kk = id & 3, f = id >> 2;
        int j = f & 1023, k = ((f >> 10) << 2) + kk;
        W4p[id] = (j < 512) ? wWihF[j*296 + k] : wWihB[(j-512)*296 + k];
    } else if (idx < 565248 + 131072) {       // word recurrent (K=128, N=1024)
        int id = idx - 565248;
        int kk = id & 3, f = id >> 2;
        int j = f & 1023, k = ((f >> 10) << 2) + kk;
        W4h[id] = (j < 512) ? wWhhF[j*128 + k] : wWhhB[(j-512)*128 + k];
    }
}

// ---------------- block scan: starts + instruction->block id ----------------
__global__ __launch_bounds__(512) void scan_kernel(
    const int* __restrict__ block_lens, int* __restrict__ starts, int* __restrict__ bid)
{
    __shared__ int s[N_BLOCKS];
    int t = threadIdx.x;
    int len = block_lens[t];
    s[t] = len;
    __syncthreads();
    for (int off = 1; off < N_BLOCKS; off <<= 1) {
        int v = (t >= off) ? s[t - off] : 0;
        __syncthreads();
        s[t] += v;
        __syncthreads();
    }
    int start = s[t] - len;
    starts[t] = start;
    for (int p = 0; p < len; ++p) bid[start + p] = t;
}

// ---------------- counting sort of instructions by token_len ----------------
__global__ __launch_bounds__(256) void sort_by_len(
    const int* __restrict__ token_lens, int* __restrict__ order)
{
    __shared__ int cnt[T_TOK + 1];
    __shared__ int base[T_TOK + 1];
    int tid = threadIdx.x;
    if (tid <= T_TOK) cnt[tid] = 0;
    __syncthreads();
    for (int i = tid; i < N_INSTR; i += 256) atomicAdd(&cnt[token_lens[i]], 1);
    __syncthreads();
    if (tid == 0) {
        int s = 0;
        for (int l = 0; l <= T_TOK; ++l) { base[l] = s; s += cnt[l]; }
    }
    __syncthreads();
    for (int i = tid; i < N_INSTR; i += 256) {
        int pos = atomicAdd(&base[token_lens[i]], 1);
        order[pos] = i;
    }
}

// ---------------- counting sort of blocks by block_len ----------------
__global__ __launch_bounds__(512) void sort_blocks(
    const int* __restrict__ block_lens, int* __restrict__ border)
{
    __shared__ int cnt[MAX_BLK + 1];
    __shared__ int base[MAX_BLK + 1];
    int tid = threadIdx.x;
    if (tid <= MAX_BLK) cnt[tid] = 0;
    __syncthreads();
    int len = block_lens[tid];
    atomicAdd(&cnt[len], 1);
    __syncthreads();
    if (tid == 0) {
        int s = 0;
        for (int l = 0; l <= MAX_BLK; ++l) { base[l] = s; s += cnt[l]; }
    }
    __syncthreads();
    int pos = atomicAdd(&base[len], 1);
    border[pos] = tid;
}

// ---------------- precompute E'[token] = emb[token] @ Wih^T (both dirs) ----------------
// EF4/EB4: [1024 tokens][128 units] float4 (gates 0..3), bias NOT included.
__global__ __launch_bounds__(256) void ex_pack(
    const float* __restrict__ emb,
    const float* __restrict__ W4cf, const float* __restrict__ W4cb,
    float* __restrict__ EF4, float* __restrict__ EB4)
{
    __shared__ float xe[128];
    int tk  = blockIdx.x;
    int tid = threadIdx.x;
    if (tid < 32) ((float4*)xe)[tid] = ((const float4*)(emb + tk * HDIM))[tid];
    __syncthreads();
    int u = tid & 127, dir = tid >> 7;
    const float4* W = (const float4*)(dir ? W4cb : W4cf);   // kc 0..31 = Wih part
    float a0 = 0.f, a1 = 0.f, a2 = 0.f, a3 = 0.f;
    for (int kc = 0; kc < 32; ++kc) {
        float4 x  = ((const float4*)xe)[kc];
        float4 w0 = W[kc*512 +   0 + u];
        float4 w1 = W[kc*512 + 128 + u];
        float4 w2 = W[kc*512 + 256 + u];
        float4 w3 = W[kc*512 + 384 + u];
        a0 = fmaf(w0.x,x.x,fmaf(w0.y,x.y,fmaf(w0.z,x.z,fmaf(w0.w,x.w,a0))));
        a1 = fmaf(w1.x,x.x,fmaf(w1.y,x.y,fmaf(w1.z,x.z,fmaf(w1.w,x.w,a1))));
        a2 = fmaf(w2.x,x.x,fmaf(w2.y,x.y,fmaf(w2.z,x.z,fmaf(w2.w,x.w,a2))));
        a3 = fmaf(w3.x,x.x,fmaf(w3.y,x.y,fmaf(w3.z,x.z,fmaf(w3.w,x.w,a3))));
    }
    float4 r = make_float4(a0, a1, a2, a3);
    ((float4*)(dir ? EB4 : EF4))[tk * 128 + u] = r;
}

// ---------------- char BiLSTM ----------------
// One WG = 16 instructions (length-sorted), 256 threads, grid 1024 (4 WG/CU).
// Thread owns (unit u = tid&127, half -> 8 instructions), all 4 gates.
// Input projection comes from EF4/EB4 tables; only h@Whh^T (K=128) per step.
// launch_bounds (256,4): acc[8][4] halves register need vs r8's acc[16][4]
// (120 VGPR) -> est ~95, fits the 128 cap. Watch WRITE_SIZE for spills (r6 lesson).
__global__ __launch_bounds__(256, 4) void char_lstm(
    const int* __restrict__ tokens, const int* __restrict__ token_lens,
    const int* __restrict__ order,
    const float* __restrict__ EF4, const float* __restrict__ EB4,
    const float* __restrict__ W4f, const float* __restrict__ W4b,
    const float* __restrict__ bf,  const float* __restrict__ bb,
    float* __restrict__ instr_h)
{
    __shared__ float hF[CIB][128];
    __shared__ float hB[CIB][128];
    __shared__ int   toks[CIB][T_TOK];
    __shared__ int   lens[CIB];
    __shared__ int   iid[CIB];
    __shared__ int   maxl_s;

    const int tid = threadIdx.x;
    const int i0  = blockIdx.x * CIB;

    if (tid == 0) maxl_s = 0;
    __syncthreads();
    if (tid < CIB) {
        int id = order[i0 + tid];
        iid[tid] = id;
        int l = token_lens[id];
        lens[tid] = l;
        atomicMax(&maxl_s, l);
    }
    __syncthreads();
    for (int idx = tid; idx < CIB * T_TOK; idx += 256)
        toks[idx >> 4][idx & 15] = tokens[iid[idx >> 4] * T_TOK + (idx & 15)];
    for (int idx = tid; idx < CIB * 128; idx += 256) {
        ((float*)hF)[idx] = 0.f;
        ((float*)hB)[idx] = 0.f;
    }
    __syncthreads();

    const int u    = tid & 127;
    const int half = tid >> 7;
    const int ib0  = half * 8;

    float bfr[4], bbr[4];
    #pragma unroll
    for (int g = 0; g < 4; ++g) { bfr[g] = bf[g*128 + u]; bbr[g] = bb[g*128 + u]; }

    float cF[8], cB[8];
    #pragma unroll
    for (int i = 0; i < 8; ++i) { cF[i] = 0.f; cB[i] = 0.f; }

    const float4* Wf = (const float4*)W4f + 32*512;   // Whh section (kc 32..63)
    const float4* Wb = (const float4*)W4b + 32*512;
    const float4* EF = (const float4*)EF4;
    const float4* EB = (const float4*)EB4;

    const int maxl = maxl_s;

    for (int t = 0; t < maxl; ++t) {
        // ---------- forward ----------
        {
            float acc[8][4];
            #pragma unroll
            for (int il = 0; il < 8; ++il) {
                float4 e = EF[toks[ib0 + il][t] * 128 + u];
                acc[il][0] = e.x; acc[il][1] = e.y; acc[il][2] = e.z; acc[il][3] = e.w;
            }
            for (int kc = 0; kc < 32; ++kc) {
                float4 w0 = Wf[kc*512 +   0 + u];
                float4 w1 = Wf[kc*512 + 128 + u];
                float4 w2 = Wf[kc*512 + 256 + u];
                float4 w3 = Wf[kc*512 + 384 + u];
                #pragma unroll
                for (int il = 0; il < 8; ++il) {
                    float4 x = *(const float4*)&hF[ib0 + il][kc*4];
                    acc[il][0] = fmaf(w0.x,x.x,fmaf(w0.y,x.y,fmaf(w0.z,x.z,fmaf(w0.w,x.w,acc[il][0]))));
                    acc[il][1] = fmaf(w1.x,x.x,fmaf(w1.y,x.y,fmaf(w1.z,x.z,fmaf(w1.w,x.w,acc[il][1]))));
                    acc[il][2] = fmaf(w2.x,x.x,fmaf(w2.y,x.y,fmaf(w2.z,x.z,fmaf(w2.w,x.w,acc[il][2]))));
                    acc[il][3] = fmaf(w3.x,x.x,fmaf(w3.y,x.y,fmaf(w3.z,x.z,fmaf(w3.w,x.w,acc[il][3]))));
                }
            }
            __syncthreads();     // all forward reads of hF done before writes
            #pragma unroll
            for (int il = 0; il < 8; ++il) {
                int i = ib0 + il;
                if (t < lens[i]) {
                    float gi = sigf   (acc[il][0] + bfr[0]);
                    float gf = sigf   (acc[il][1] + bfr[1]);
                    float gg = tanhf_s(acc[il][2] + bfr[2]);
                    float go = sigf   (acc[il][3] + bfr[3]);
                    float cn = gf * cF[il] + gi * gg;
                    cF[il] = cn;
                    hF[i][u] = go * tanhf_s(cn);
                }
            }
        }
        // ---------- backward ----------
        {
            float acc[8][4];
            #pragma unroll
            for (int il = 0; il < 8; ++il) {
                int i = ib0 + il;
                int tt = lens[i] - 1 - t;
                tt = tt < 0 ? 0 : tt;
                float4 e = EB[toks[i][tt] * 128 + u];
                acc[il][0] = e.x; acc[il][1] = e.y; acc[il][2] = e.z; acc[il][3] = e.w;
            }
            for (int kc = 0; kc < 32; ++kc) {
                float4 w0 = Wb[kc*512 +   0 + u];
                float4 w1 = Wb[kc*512 + 128 + u];
                float4 w2 = Wb[kc*512 + 256 + u];
                float4 w3 = Wb[kc*512 + 384 + u];
                #pragma unroll
                for (int il = 0; il < 8; ++il) {
                    float4 x = *(const float4*)&hB[ib0 + il][kc*4];
                    acc[il][0] = fmaf(w0.x,x.x,fmaf(w0.y,x.y,fmaf(w0.z,x.z,fmaf(w0.w,x.w,acc[il][0]))));
                    acc[il][1] = fmaf(w1.x,x.x,fmaf(w1.y,x.y,fmaf(w1.z,x.z,fmaf(w1.w,x.w,acc[il][1]))));
                    acc[il][2] = fmaf(w2.x,x.x,fmaf(w2.y,x.y,fmaf(w2.z,x.z,fmaf(w2.w,x.w,acc[il][2]))));
                    acc[il][3] = fmaf(w3.x,x.x,fmaf(w3.y,x.y,fmaf(w3.z,x.z,fmaf(w3.w,x.w,acc[il][3]))));
                }
            }
            __syncthreads();     // all backward reads of hB done before writes
            #pragma unroll
            for (int il = 0; il < 8; ++il) {
                int i = ib0 + il;
                if (t < lens[i]) {
                    float gi = sigf   (acc[il][0] + bbr[0]);
                    float gf = sigf   (acc[il][1] + bbr[1]);
                    float gg = tanhf_s(acc[il][2] + bbr[2]);
                    float go = sigf   (acc[il][3] + bbr[3]);
                    float cn = gf * cB[il] + gi * gg;
                    cB[il] = cn;
                    hB[i][u] = go * tanhf_s(cn);
                }
            }
        }
        __syncthreads();         // h writes visible before next step's k-loops
    }

    // write instr_h = [h_f | h_b] at ORIGINAL instruction ids
    for (int idx = tid; idx < CIB * 128; idx += 256) {
        int i = idx >> 7, uu = idx & 127;
        int id = iid[i];
        instr_h[id * 256 +       uu] = hF[i][uu];
        instr_h[id * 256 + 128 + uu] = hB[i][uu];
    }
}

// ---------------- gather word inputs xw[i][296] ----------------
__global__ __launch_bounds__(256) void xw_gather(
    const float* __restrict__ instr_h, const float* __restrict__ instr_params,
    const float* __restrict__ gparams, const int* __restrict__ bid,
    float* __restrict__ xw)
{
    int idx = blockIdx.x * 256 + threadIdx.x;       // float4 index
    if (idx >= N_INSTR * 74) return;
    int i = idx / 74, c = idx % 74;
    float4 v;
    if (c < 64)      v = ((const float4*)(instr_h + i*256))[c];
    else if (c < 72) v = ((const float4*)(instr_params + i*32))[c - 64];
    else             v = ((const float4*)(gparams + bid[i]*8))[c - 72];
    ((float4*)(xw + i*296))[c] = v;
}

// ---------------- word input projection P[i][1024] = xw @ [WihF|WihB]^T + b ----------------
__global__ __launch_bounds__(256) void word_proj(
    const float* __restrict__ xw, const float* __restrict__ W4p,
    const float* __restrict__ b_f, const float* __restrict__ b_b,
    float* __restrict__ P)
{
    __shared__ float xs[16][296];
    int tid = threadIdx.x;
    int rowTile = blockIdx.x >> 2;
    int colTile = blockIdx.x & 3;
    int i0 = rowTile * 16;

    for (int idx = tid; idx < 16 * 74; idx += 256) {
        int i = idx / 74, c = idx % 74;
        ((float4*)&xs[i][0])[c] = ((const float4*)(xw + (size_t)(i0 + i) * 296))[c];
    }
    __syncthreads();

    int j = colTile * 256 + tid;
    float acc[16];
    #pragma unroll
    for (int i = 0; i < 16; ++i) acc[i] = 0.f;
    const float4* W4 = (const float4*)W4p;
    for (int kc = 0; kc < 74; ++kc) {
        float4 w = W4[kc*1024 + j];
        #pragma unroll
        for (int i = 0; i < 16; ++i) {
            float4 x = ((const float4*)&xs[i][0])[kc];
            acc[i] = fmaf(w.x,x.x,fmaf(w.y,x.y,fmaf(w.z,x.z,fmaf(w.w,x.w,acc[i]))));
        }
    }
    float bias = (j < 512) ? b_f[j] : b_b[j - 512];
    for (int i = 0; i < 16; ++i)
        P[(size_t)(i0 + i) * 1024 + j] = acc[i] + bias;
}

// ---------------- word BiLSTM, fully fused ----------------
// Per-block recurrence is independent across blocks -> no cross-WG sync needed.
// Grid 256: WG w = (dir d = w&1, 4 sorted blocks g*4..g*4+3, g = w>>1).
// Thread (u = tid&127, half): owns unit u of 2 blocks; h in LDS, c in regs.
// Replaces 64 per-step launches (288 us dispatch + ~launch gaps).
// Per-block fmaf order identical to the old word_step -> bit-identical results.
__global__ __launch_bounds__(256, 2) void word_lstm(
    const float* __restrict__ W4h, const float* __restrict__ P,
    const int* __restrict__ starts, const int* __restrict__ block_lens,
    const int* __restrict__ border,
    float* __restrict__ hfin)
{
    __shared__ float hs[4][128];
    __shared__ int   binfo[4][3];    // orig block id, start, len

    const int w   = blockIdx.x;
    const int d   = w & 1;
    const int g   = w >> 1;
    const int tid = threadIdx.x;
    const int u    = tid & 127;
    const int half = tid >> 7;
    const int q0   = half * 2;

    if (tid < 4) {
        int ob = border[g * 4 + tid];
        binfo[tid][0] = ob;
        binfo[tid][1] = starts[ob];
        binfo[tid][2] = block_lens[ob];
    }
    for (int idx = tid; idx < 4 * 128; idx += 256) ((float*)hs)[idx] = 0.f;
    __syncthreads();

    const int len0 = binfo[q0][2],     len1 = binfo[q0 + 1][2];
    const int st0  = binfo[q0][1],     st1  = binfo[q0 + 1][1];
    const int maxlen = max(max(binfo[0][2], binfo[1][2]),
                           max(binfo[2][2], binfo[3][2]));

    float c0 = 0.f, c1 = 0.f;
    const float4* W4 = (const float4*)W4h;

    for (int t = 0; t < maxlen; ++t) {
        float a0[4] = {0.f, 0.f, 0.f, 0.f};
        float a1[4] = {0.f, 0.f, 0.f, 0.f};
        for (int kc = 0; kc < 32; ++kc) {
            float4 w0 = W4[kc*1024 + d*512 +   0 + u];
            float4 w1 = W4[kc*1024 + d*512 + 128 + u];
            float4 w2 = W4[kc*1024 + d*512 + 256 + u];
            float4 w3 = W4[kc*1024 + d*512 + 384 + u];
            float4 h0 = *(const float4*)&hs[q0][kc*4];
            float4 h1 = *(const float4*)&hs[q0 + 1][kc*4];
            a0[0] = fmaf(w0.x,h0.x,fmaf(w0.y,h0.y,fmaf(w0.z,h0.z,fmaf(w0.w,h0.w,a0[0]))));
            a0[1] = fmaf(w1.x,h0.x,fmaf(w1.y,h0.y,fmaf(w1.z,h0.z,fmaf(w1.w,h0.w,a0[1]))));
            a0[2] = fmaf(w2.x,h0.x,fmaf(w2.y,h0.y,fmaf(w2.z,h0.z,fmaf(w2.w,h0.w,a0[2]))));
            a0[3] = fmaf(w3.x,h0.x,fmaf(w3.y,h0.y,fmaf(w3.z,h0.z,fmaf(w3.w,h0.w,a0[3]))));
            a1[0] = fmaf(w0.x,h1.x,fmaf(w0.y,h1.y,fmaf(w0.z,h1.z,fmaf(w0.w,h1.w,a1[0]))));
            a1[1] = fmaf(w1.x,h1.x,fmaf(w1.y,h1.y,fmaf(w1.z,h1.z,fmaf(w1.w,h1.w,a1[1]))));
            a1[2] = fmaf(w2.x,h1.x,fmaf(w2.y,h1.y,fmaf(w2.z,h1.z,fmaf(w2.w,h1.w,a1[2]))));
            a1[3] = fmaf(w3.x,h1.x,fmaf(w3.y,h1.y,fmaf(w3.z,h1.z,fmaf(w3.w,h1.w,a1[3]))));
        }
        __syncthreads();   // reads of hs done before updates
        if (t < len0) {
            int rs = (d == 0) ? (st0 + t) : (st0 + len0 - 1 - t);
            const float* Prow = P + (size_t)rs * 1024 + d * 512;
            float gi = sigf   (a0[0] + Prow[  0 + u]);
            float gf = sigf   (a0[1] + Prow[128 + u]);
            float gg = tanhf_s(a0[2] + Prow[256 + u]);
            float go = sigf   (a0[3] + Prow[384 + u]);
            float cn = gf * c0 + gi * gg;
            c0 = cn;
            hs[q0][u] = go * tanhf_s(cn);
        }
        if (t < len1) {
            int rs = (d == 0) ? (st1 + t) : (st1 + len1 - 1 - t);
            const float* Prow = P + (size_t)rs * 1024 + d * 512;
            float gi = sigf   (a1[0] + Prow[  0 + u]);
            float gf = sigf   (a1[1] + Prow[128 + u]);
            float gg = tanhf_s(a1[2] + Prow[256 + u]);
            float go = sigf   (a1[3] + Prow[384 + u]);
            float cn = gf * c1 + gi * gg;
            c1 = cn;
            hs[q0 + 1][u] = go * tanhf_s(cn);
        }
        __syncthreads();   // updates visible before next step's reads
    }

    // write final h at (dir, orig block) layout expected by final_k
    hfin[(size_t)(d * 512 + binfo[q0][0])     * 128 + u] = hs[q0][u];
    hfin[(size_t)(d * 512 + binfo[q0 + 1][0]) * 128 + u] = hs[q0 + 1][u];
}

// ---------------- final linear ----------------
__global__ __launch_bounds__(256) void final_k(
    const float* __restrict__ hfinal, const float* __restrict__ gp,
    const float* __restrict__ fW, const float* __restrict__ fb,
    float* __restrict__ out)
{
    int tid = threadIdx.x;
    int w = tid >> 6, l = tid & 63;
    int b = blockIdx.x * 4 + w;
    const float* hf = hfinal + (size_t)(0 * 512 + b) * 128;
    const float* hb = hfinal + (size_t)(1 * 512 + b) * 128;
    float s = hf[l] * fW[l] + hf[l + 64] * fW[l + 64]
            + hb[l] * fW[128 + l] + hb[l + 64] * fW[192 + l];
    if (l < 8) s += gp[b * 8 + l] * fW[256 + l];
    #pragma unroll
    for (int off = 32; off > 0; off >>= 1) s += __shfl_down(s, off);
    if (l == 0) out[b] = s + fb[0];
}

// ---------------- launcher ----------------
extern "C" void kernel_launch(void* const* d_in, const int* in_sizes, int n_in,
                              void* d_out, int out_size, void* d_ws, size_t ws_size,
                              hipStream_t stream)
{
    const int*   tokens        = (const int*)  d_in[0];
    const int*   token_lens    = (const int*)  d_in[1];
    const int*   block_lens    = (const int*)  d_in[2];
    const float* instr_params  = (const float*)d_in[3];
    const float* global_params = (const float*)d_in[4];
    const float* emb           = (const float*)d_in[5];
    const float* cWihF = (const float*)d_in[6];
    const float* cWhhF = (const float*)d_in[7];
    const float* cbF   = (const float*)d_in[8];
    const float* cWihB = (const float*)d_in[9];
    const float* cWhhB = (const float*)d_in[10];
    const float* cbB   = (const float*)d_in[11];
    const float* wWihF = (const float*)d_in[12];
    const float* wWhhF = (const float*)d_in[13];
    const float* wbF   = (const float*)d_in[14];
    const float* wWihB = (const float*)d_in[15];
    const float* wWhhB = (const float*)d_in[16];
    const float* wbB   = (const float*)d_in[17];
    const float* fW    = (const float*)d_in[18];
    const float* fb    = (const float*)d_in[19];
    float* out = (float*)d_out;

    char* ws = (char*)d_ws;
    size_t off = 0;
    auto alloc_f = [&](size_t nfloats) { float* p = (float*)(ws + off); off += nfloats * 4; return p; };

    float* W4cf    = alloc_f(131072);
    float* W4cb    = alloc_f(131072);
    float* W4p     = alloc_f(303104);
    float* W4h     = alloc_f(131072);
    float* instr_h = alloc_f((size_t)N_INSTR * 256);
    float* xw      = alloc_f((size_t)N_INSTR * 296);
    float* P       = alloc_f((size_t)N_INSTR * 1024);
    float* hfin    = alloc_f(2 * 512 * 128);        // final word h, (dir, block) layout
    float* EF4     = alloc_f((size_t)N_TOKENS * 128 * 4);
    float* EB4     = alloc_f((size_t)N_TOKENS * 128 * 4);
    int*   starts  = (int*)(ws + off); off += 512 * 4;
    int*   bid     = (int*)(ws + off); off += N_INSTR * 4;
    int*   order   = (int*)(ws + off); off += N_INSTR * 4;
    int*   border  = (int*)(ws + off); off += 512 * 4;

    prep_pack<<<2720, 256, 0, stream>>>(cWihF, cWhhF, cWihB, cWhhB,
                                        wWihF, wWihB, wWhhF, wWhhB,
                                        W4cf, W4cb, W4p, W4h);
    scan_kernel<<<1, 512, 0, stream>>>(block_lens, starts, bid);
    sort_by_len<<<1, 256, 0, stream>>>(token_lens, order);
    sort_blocks<<<1, 512, 0, stream>>>(block_lens, border);
    ex_pack<<<N_TOKENS, 256, 0, stream>>>(emb, W4cf, W4cb, EF4, EB4);

    char_lstm<<<N_INSTR / CIB, 256, 0, stream>>>(tokens, token_lens, order,
                                                 EF4, EB4, W4cf, W4cb,
                                                 cbF, cbB, instr_h);
    xw_gather<<<4736, 256, 0, stream>>>(instr_h, instr_params, global_params, bid, xw);
    word_proj<<<4096, 256, 0, stream>>>(xw, W4p, wbF, wbB, P);
    word_lstm<<<256, 256, 0, stream>>>(W4h, P, starts, block_lens, border, hfin);
    final_k<<<128, 256, 0, stream>>>(hfin, global_params, fW, fb, out);
}

// Round 13
// 1431.353 us; speedup vs baseline: 3.4923x; 1.0015x over previous
//
#include <hip/hip_runtime.h>
#include <hip/hip_bf16.h>
#include <math.h>

// ---------------- problem constants ----------------
#define N_INSTR   16384
#define T_TOK     16
#define N_BLOCKS  512
#define MAX_BLK   64
#define HDIM      128
#define P_INSTR   32
#define P_GLOB    8
#define D_WORD    296     // 2*H + P_INSTR + P_GLOB
#define N_TOKENS  1024

#define CIB       16      // instructions per WG in char kernel (grid 1024 = 4 WG/CU possible)

__device__ __forceinline__ float sigf(float x) {
    return 1.0f / (1.0f + __expf(-x));
}
__device__ __forceinline__ float tanhf_s(float x) {
    float a = fabsf(x);
    float e = __expf(-2.0f * a);
    float t = (1.0f - e) / (1.0f + e);
    return copysignf(t, x);
}

// ---------------- weight packing ----------------
// Packed layout (float4 chunks over k): flat idx = ((k>>2)*NCOL + j)*4 + (k&3)
// charW4: NCOL=512, K=256 (kc 0..31: Wih, kc 32..63: Whh)
// wordW4p: NCOL=1024 (j<512 fwd, else bwd), K=296 (Wih only)
// wordW4h: NCOL=1024, K=128 (Whh only)
__global__ __launch_bounds__(256) void prep_pack(
    const float* __restrict__ cWihF, const float* __restrict__ cWhhF,
    const float* __restrict__ cWihB, const float* __restrict__ cWhhB,
    const float* __restrict__ wWihF, const float* __restrict__ wWihB,
    const float* __restrict__ wWhhF, const float* __restrict__ wWhhB,
    float* __restrict__ W4cf, float* __restrict__ W4cb,
    float* __restrict__ W4p,  float* __restrict__ W4h)
{
    int idx = blockIdx.x * 256 + threadIdx.x;
    if (idx < 131072) {                       // char fwd
        int kk = idx & 3, f = idx >> 2;
        int j = f & 511, k = ((f >> 9) << 2) + kk;
        W4cf[idx] = (k < 128) ? cWihF[j*128 + k] : cWhhF[j*128 + (k-128)];
    } else if (idx < 262144) {                // char bwd
        int id = idx - 131072;
        int kk = id & 3, f = id >> 2;
        int j = f & 511, k = ((f >> 9) << 2) + kk;
        W4cb[id] = (k < 128) ? cWihB[j*128 + k] : cWhhB[j*128 + (k-128)];
    } else if (idx < 262144 + 303104) {       // word input proj (K=296, N=1024)
        int id = idx - 262144;
        int kk = id & 3, f = id >> 2;
        int j = f & 1023, k = ((f >> 10) << 2) + kk;
        W4p[id] = (j < 512) ? wWihF[j*296 + k] : wWihB[(j-512)*296 + k];
    } else if (idx < 565248 + 131072) {       // word recurrent (K=128, N=1024)
        int id = idx - 565248;
        int kk = id & 3, f = id >> 2;
        int j = f & 1023, k = ((f >> 10) << 2) + kk;
        W4h[id] = (j < 512) ? wWhhF[j*128 + k] : wWhhB[(j-512)*128 + k];
    }
}

// ---------------- block scan: starts + instruction->block id ----------------
__global__ __launch_bounds__(512) void scan_kernel(
    const int* __restrict__ block_lens, int* __restrict__ starts, int* __restrict__ bid)
{
    __shared__ int s[N_BLOCKS];
    int t = threadIdx.x;
    int len = block_lens[t];
    s[t] = len;
    __syncthreads();
    for (int off = 1; off < N_BLOCKS; off <<= 1) {
        int v = (t >= off) ? s[t - off] : 0;
        __syncthreads();
        s[t] += v;
        __syncthreads();
    }
    int start = s[t] - len;
    starts[t] = start;
    for (int p = 0; p < len; ++p) bid[start + p] = t;
}

// ---------------- counting sort of instructions by token_len ----------------
__global__ __launch_bounds__(256) void sort_by_len(
    const int* __restrict__ token_lens, int* __restrict__ order)
{
    __shared__ int cnt[T_TOK + 1];
    __shared__ int base[T_TOK + 1];
    int tid = threadIdx.x;
    if (tid <= T_TOK) cnt[tid] = 0;
    __syncthreads();
    for (int i = tid; i < N_INSTR; i += 256) atomicAdd(&cnt[token_lens[i]], 1);
    __syncthreads();
    if (tid == 0) {
        int s = 0;
        for (int l = 0; l <= T_TOK; ++l) { base[l] = s; s += cnt[l]; }
    }
    __syncthreads();
    for (int i = tid; i < N_INSTR; i += 256) {
        int pos = atomicAdd(&base[token_lens[i]], 1);
        order[pos] = i;
    }
}

// ---------------- counting sort of blocks by block_len ----------------
__global__ __launch_bounds__(512) void sort_blocks(
    const int* __restrict__ block_lens, int* __restrict__ border)
{
    __shared__ int cnt[MAX_BLK + 1];
    __shared__ int base[MAX_BLK + 1];
    int tid = threadIdx.x;
    if (tid <= MAX_BLK) cnt[tid] = 0;
    __syncthreads();
    int len = block_lens[tid];
    atomicAdd(&cnt[len], 1);
    __syncthreads();
    if (tid == 0) {
        int s = 0;
        for (int l = 0; l <= MAX_BLK; ++l) { base[l] = s; s += cnt[l]; }
    }
    __syncthreads();
    int pos = atomicAdd(&base[len], 1);
    border[pos] = tid;
}

// ---------------- precompute E'[token] = emb[token] @ Wih^T (both dirs) ----------------
// EF4/EB4: [1024 tokens][128 units] float4 (gates 0..3), bias NOT included.
__global__ __launch_bounds__(256) void ex_pack(
    const float* __restrict__ emb,
    const float* __restrict__ W4cf, const float* __restrict__ W4cb,
    float* __restrict__ EF4, float* __restrict__ EB4)
{
    __shared__ float xe[128];
    int tk  = blockIdx.x;
    int tid = threadIdx.x;
    if (tid < 32) ((float4*)xe)[tid] = ((const float4*)(emb + tk * HDIM))[tid];
    __syncthreads();
    int u = tid & 127, dir = tid >> 7;
    const float4* W = (const float4*)(dir ? W4cb : W4cf);   // kc 0..31 = Wih part
    float a0 = 0.f, a1 = 0.f, a2 = 0.f, a3 = 0.f;
    for (int kc = 0; kc < 32; ++kc) {
        float4 x  = ((const float4*)xe)[kc];
        float4 w0 = W[kc*512 +   0 + u];
        float4 w1 = W[kc*512 + 128 + u];
        float4 w2 = W[kc*512 + 256 + u];
        float4 w3 = W[kc*512 + 384 + u];
        a0 = fmaf(w0.x,x.x,fmaf(w0.y,x.y,fmaf(w0.z,x.z,fmaf(w0.w,x.w,a0))));
        a1 = fmaf(w1.x,x.x,fmaf(w1.y,x.y,fmaf(w1.z,x.z,fmaf(w1.w,x.w,a1))));
        a2 = fmaf(w2.x,x.x,fmaf(w2.y,x.y,fmaf(w2.z,x.z,fmaf(w2.w,x.w,a2))));
        a3 = fmaf(w3.x,x.x,fmaf(w3.y,x.y,fmaf(w3.z,x.z,fmaf(w3.w,x.w,a3))));
    }
    float4 r = make_float4(a0, a1, a2, a3);
    ((float4*)(dir ? EB4 : EF4))[tk * 128 + u] = r;
}

// ---------------- char BiLSTM ----------------
// One WG = 16 instructions (length-sorted), 256 threads, grid 1024.
// Thread owns (unit u = tid&127, half -> 8 instructions), all 4 gates.
// Input projection from EF4/EB4 tables; only h@Whh^T (K=128) per step.
// launch_bounds history: (256,3) r6 -> 84 VGPR, 10 GB spills; (256,4) r10 ->
// 64 VGPR, 0.47 GB spills (compiler over-chases occupancy and spills acc).
// (256,2) r8 -> 120 VGPR, spill-free. Keep (256,2); with acc[8][4] expect
// ~100 VGPR, which still hardware-fits 4 blocks/CU without forcing spills.
__global__ __launch_bounds__(256, 2) void char_lstm(
    const int* __restrict__ tokens, const int* __restrict__ token_lens,
    const int* __restrict__ order,
    const float* __restrict__ EF4, const float* __restrict__ EB4,
    const float* __restrict__ W4f, const float* __restrict__ W4b,
    const float* __restrict__ bf,  const float* __restrict__ bb,
    float* __restrict__ instr_h)
{
    __shared__ float hF[CIB][128];
    __shared__ float hB[CIB][128];
    __shared__ int   toks[CIB][T_TOK];
    __shared__ int   lens[CIB];
    __shared__ int   iid[CIB];
    __shared__ int   maxl_s;

    const int tid = threadIdx.x;
    const int i0  = blockIdx.x * CIB;

    if (tid == 0) maxl_s = 0;
    __syncthreads();
    if (tid < CIB) {
        int id = order[i0 + tid];
        iid[tid] = id;
        int l = token_lens[id];
        lens[tid] = l;
        atomicMax(&maxl_s, l);
    }
    __syncthreads();
    for (int idx = tid; idx < CIB * T_TOK; idx += 256)
        toks[idx >> 4][idx & 15] = tokens[iid[idx >> 4] * T_TOK + (idx & 15)];
    for (int idx = tid; idx < CIB * 128; idx += 256) {
        ((float*)hF)[idx] = 0.f;
        ((float*)hB)[idx] = 0.f;
    }
    __syncthreads();

    const int u    = tid & 127;
    const int half = tid >> 7;
    const int ib0  = half * 8;

    float bfr[4], bbr[4];
    #pragma unroll
    for (int g = 0; g < 4; ++g) { bfr[g] = bf[g*128 + u]; bbr[g] = bb[g*128 + u]; }

    float cF[8], cB[8];
    #pragma unroll
    for (int i = 0; i < 8; ++i) { cF[i] = 0.f; cB[i] = 0.f; }

    const float4* Wf = (const float4*)W4f + 32*512;   // Whh section (kc 32..63)
    const float4* Wb = (const float4*)W4b + 32*512;
    const float4* EF = (const float4*)EF4;
    const float4* EB = (const float4*)EB4;

    const int maxl = maxl_s;

    for (int t = 0; t < maxl; ++t) {
        // ---------- forward ----------
        {
            float acc[8][4];
            #pragma unroll
            for (int il = 0; il < 8; ++il) {
                float4 e = EF[toks[ib0 + il][t] * 128 + u];
                acc[il][0] = e.x; acc[il][1] = e.y; acc[il][2] = e.z; acc[il][3] = e.w;
            }
            for (int kc = 0; kc < 32; ++kc) {
                float4 w0 = Wf[kc*512 +   0 + u];
                float4 w1 = Wf[kc*512 + 128 + u];
                float4 w2 = Wf[kc*512 + 256 + u];
                float4 w3 = Wf[kc*512 + 384 + u];
                #pragma unroll
                for (int il = 0; il < 8; ++il) {
                    float4 x = *(const float4*)&hF[ib0 + il][kc*4];
                    acc[il][0] = fmaf(w0.x,x.x,fmaf(w0.y,x.y,fmaf(w0.z,x.z,fmaf(w0.w,x.w,acc[il][0]))));
                    acc[il][1] = fmaf(w1.x,x.x,fmaf(w1.y,x.y,fmaf(w1.z,x.z,fmaf(w1.w,x.w,acc[il][1]))));
                    acc[il][2] = fmaf(w2.x,x.x,fmaf(w2.y,x.y,fmaf(w2.z,x.z,fmaf(w2.w,x.w,acc[il][2]))));
                    acc[il][3] = fmaf(w3.x,x.x,fmaf(w3.y,x.y,fmaf(w3.z,x.z,fmaf(w3.w,x.w,acc[il][3]))));
                }
            }
            __syncthreads();     // all forward reads of hF done before writes
            #pragma unroll
            for (int il = 0; il < 8; ++il) {
                int i = ib0 + il;
                if (t < lens[i]) {
                    float gi = sigf   (acc[il][0] + bfr[0]);
                    float gf = sigf   (acc[il][1] + bfr[1]);
                    float gg = tanhf_s(acc[il][2] + bfr[2]);
                    float go = sigf   (acc[il][3] + bfr[3]);
                    float cn = gf * cF[il] + gi * gg;
                    cF[il] = cn;
                    hF[i][u] = go * tanhf_s(cn);
                }
            }
        }
        // ---------- backward ----------
        {
            float acc[8][4];
            #pragma unroll
            for (int il = 0; il < 8; ++il) {
                int i = ib0 + il;
                int tt = lens[i] - 1 - t;
                tt = tt < 0 ? 0 : tt;
                float4 e = EB[toks[i][tt] * 128 + u];
                acc[il][0] = e.x; acc[il][1] = e.y; acc[il][2] = e.z; acc[il][3] = e.w;
            }
            for (int kc = 0; kc < 32; ++kc) {
                float4 w0 = Wb[kc*512 +   0 + u];
                float4 w1 = Wb[kc*512 + 128 + u];
                float4 w2 = Wb[kc*512 + 256 + u];
                float4 w3 = Wb[kc*512 + 384 + u];
                #pragma unroll
                for (int il = 0; il < 8; ++il) {
                    float4 x = *(const float4*)&hB[ib0 + il][kc*4];
                    acc[il][0] = fmaf(w0.x,x.x,fmaf(w0.y,x.y,fmaf(w0.z,x.z,fmaf(w0.w,x.w,acc[il][0]))));
                    acc[il][1] = fmaf(w1.x,x.x,fmaf(w1.y,x.y,fmaf(w1.z,x.z,fmaf(w1.w,x.w,acc[il][1]))));
                    acc[il][2] = fmaf(w2.x,x.x,fmaf(w2.y,x.y,fmaf(w2.z,x.z,fmaf(w2.w,x.w,acc[il][2]))));
                    acc[il][3] = fmaf(w3.x,x.x,fmaf(w3.y,x.y,fmaf(w3.z,x.z,fmaf(w3.w,x.w,acc[il][3]))));
                }
            }
            __syncthreads();     // all backward reads of hB done before writes
            #pragma unroll
            for (int il = 0; il < 8; ++il) {
                int i = ib0 + il;
                if (t < lens[i]) {
                    float gi = sigf   (acc[il][0] + bbr[0]);
                    float gf = sigf   (acc[il][1] + bbr[1]);
                    float gg = tanhf_s(acc[il][2] + bbr[2]);
                    float go = sigf   (acc[il][3] + bbr[3]);
                    float cn = gf * cB[il] + gi * gg;
                    cB[il] = cn;
                    hB[i][u] = go * tanhf_s(cn);
                }
            }
        }
        __syncthreads();         // h writes visible before next step's k-loops
    }

    // write instr_h = [h_f | h_b] at ORIGINAL instruction ids
    for (int idx = tid; idx < CIB * 128; idx += 256) {
        int i = idx >> 7, uu = idx & 127;
        int id = iid[i];
        instr_h[id * 256 +       uu] = hF[i][uu];
        instr_h[id * 256 + 128 + uu] = hB[i][uu];
    }
}

// ---------------- gather word inputs xw[i][296] ----------------
__global__ __launch_bounds__(256) void xw_gather(
    const float* __restrict__ instr_h, const float* __restrict__ instr_params,
    const float* __restrict__ gparams, const int* __restrict__ bid,
    float* __restrict__ xw)
{
    int idx = blockIdx.x * 256 + threadIdx.x;       // float4 index
    if (idx >= N_INSTR * 74) return;
    int i = idx / 74, c = idx % 74;
    float4 v;
    if (c < 64)      v = ((const float4*)(instr_h + i*256))[c];
    else if (c < 72) v = ((const float4*)(instr_params + i*32))[c - 64];
    else             v = ((const float4*)(gparams + bid[i]*8))[c - 72];
    ((float4*)(xw + i*296))[c] = v;
}

// ---------------- word input projection P[i][1024] = xw @ [WihF|WihB]^T + b ----------------
__global__ __launch_bounds__(256) void word_proj(
    const float* __restrict__ xw, const float* __restrict__ W4p,
    const float* __restrict__ b_f, const float* __restrict__ b_b,
    float* __restrict__ P)
{
    __shared__ float xs[16][296];
    int tid = threadIdx.x;
    int rowTile = blockIdx.x >> 2;
    int colTile = blockIdx.x & 3;
    int i0 = rowTile * 16;

    for (int idx = tid; idx < 16 * 74; idx += 256) {
        int i = idx / 74, c = idx % 74;
        ((float4*)&xs[i][0])[c] = ((const float4*)(xw + (size_t)(i0 + i) * 296))[c];
    }
    __syncthreads();

    int j = colTile * 256 + tid;
    float acc[16];
    #pragma unroll
    for (int i = 0; i < 16; ++i) acc[i] = 0.f;
    const float4* W4 = (const float4*)W4p;
    for (int kc = 0; kc < 74; ++kc) {
        float4 w = W4[kc*1024 + j];
        #pragma unroll
        for (int i = 0; i < 16; ++i) {
            float4 x = ((const float4*)&xs[i][0])[kc];
            acc[i] = fmaf(w.x,x.x,fmaf(w.y,x.y,fmaf(w.z,x.z,fmaf(w.w,x.w,acc[i]))));
        }
    }
    float bias = (j < 512) ? b_f[j] : b_b[j - 512];
    for (int i = 0; i < 16; ++i)
        P[(size_t)(i0 + i) * 1024 + j] = acc[i] + bias;
}

// ---------------- word BiLSTM, fully fused ----------------
// Per-block recurrence is independent across blocks -> no cross-WG sync needed.
// Grid 256: WG w = (dir d = w&1, 4 sorted blocks g*4..g*4+3, g = w>>1).
// Thread (u = tid&127, half): owns unit u of 2 blocks; h in LDS, c in regs.
// Per-block fmaf order identical to the old word_step -> bit-identical results.
__global__ __launch_bounds__(256, 2) void word_lstm(
    const float* __restrict__ W4h, const float* __restrict__ P,
    const int* __restrict__ starts, const int* __restrict__ block_lens,
    const int* __restrict__ border,
    float* __restrict__ hfin)
{
    __shared__ float hs[4][128];
    __shared__ int   binfo[4][3];    // orig block id, start, len

    const int w   = blockIdx.x;
    const int d   = w & 1;
    const int g   = w >> 1;
    const int tid = threadIdx.x;
    const int u    = tid & 127;
    const int half = tid >> 7;
    const int q0   = half * 2;

    if (tid < 4) {
        int ob = border[g * 4 + tid];
        binfo[tid][0] = ob;
        binfo[tid][1] = starts[ob];
        binfo[tid][2] = block_lens[ob];
    }
    for (int idx = tid; idx < 4 * 128; idx += 256) ((float*)hs)[idx] = 0.f;
    __syncthreads();

    const int len0 = binfo[q0][2],     len1 = binfo[q0 + 1][2];
    const int st0  = binfo[q0][1],     st1  = binfo[q0 + 1][1];
    const int maxlen = max(max(binfo[0][2], binfo[1][2]),
                           max(binfo[2][2], binfo[3][2]));

    float c0 = 0.f, c1 = 0.f;
    const float4* W4 = (const float4*)W4h;

    for (int t = 0; t < maxlen; ++t) {
        float a0[4] = {0.f, 0.f, 0.f, 0.f};
        float a1[4] = {0.f, 0.f, 0.f, 0.f};
        for (int kc = 0; kc < 32; ++kc) {
            float4 w0 = W4[kc*1024 + d*512 +   0 + u];
            float4 w1 = W4[kc*1024 + d*512 + 128 + u];
            float4 w2 = W4[kc*1024 + d*512 + 256 + u];
            float4 w3 = W4[kc*1024 + d*512 + 384 + u];
            float4 h0 = *(const float4*)&hs[q0][kc*4];
            float4 h1 = *(const float4*)&hs[q0 + 1][kc*4];
            a0[0] = fmaf(w0.x,h0.x,fmaf(w0.y,h0.y,fmaf(w0.z,h0.z,fmaf(w0.w,h0.w,a0[0]))));
            a0[1] = fmaf(w1.x,h0.x,fmaf(w1.y,h0.y,fmaf(w1.z,h0.z,fmaf(w1.w,h0.w,a0[1]))));
            a0[2] = fmaf(w2.x,h0.x,fmaf(w2.y,h0.y,fmaf(w2.z,h0.z,fmaf(w2.w,h0.w,a0[2]))));
            a0[3] = fmaf(w3.x,h0.x,fmaf(w3.y,h0.y,fmaf(w3.z,h0.z,fmaf(w3.w,h0.w,a0[3]))));
            a1[0] = fmaf(w0.x,h1.x,fmaf(w0.y,h1.y,fmaf(w0.z,h1.z,fmaf(w0.w,h1.w,a1[0]))));
            a1[1] = fmaf(w1.x,h1.x,fmaf(w1.y,h1.y,fmaf(w1.z,h1.z,fmaf(w1.w,h1.w,a1[1]))));
            a1[2] = fmaf(w2.x,h1.x,fmaf(w2.y,h1.y,fmaf(w2.z,h1.z,fmaf(w2.w,h1.w,a1[2]))));
            a1[3] = fmaf(w3.x,h1.x,fmaf(w3.y,h1.y,fmaf(w3.z,h1.z,fmaf(w3.w,h1.w,a1[3]))));
        }
        __syncthreads();   // reads of hs done before updates
        if (t < len0) {
            int rs = (d == 0) ? (st0 + t) : (st0 + len0 - 1 - t);
            const float* Prow = P + (size_t)rs * 1024 + d * 512;
            float gi = sigf   (a0[0] + Prow[  0 + u]);
            float gf = sigf   (a0[1] + Prow[128 + u]);
            float gg = tanhf_s(a0[2] + Prow[256 + u]);
            float go = sigf   (a0[3] + Prow[384 + u]);
            float cn = gf * c0 + gi * gg;
            c0 = cn;
            hs[q0][u] = go * tanhf_s(cn);
        }
        if (t < len1) {
            int rs = (d == 0) ? (st1 + t) : (st1 + len1 - 1 - t);
            const float* Prow = P + (size_t)rs * 1024 + d * 512;
            float gi = sigf   (a1[0] + Prow[  0 + u]);
            float gf = sigf   (a1[1] + Prow[128 + u]);
            float gg = tanhf_s(a1[2] + Prow[256 + u]);
            float go = sigf   (a1[3] + Prow[384 + u]);
            float cn = gf * c1 + gi * gg;
            c1 = cn;
            hs[q0 + 1][u] = go * tanhf_s(cn);
        }
        __syncthreads();   // updates visible before next step's reads
    }

    // write final h at (dir, orig block) layout expected by final_k
    hfin[(size_t)(d * 512 + binfo[q0][0])     * 128 + u] = hs[q0][u];
    hfin[(size_t)(d * 512 + binfo[q0 + 1][0]) * 128 + u] = hs[q0 + 1][u];
}

// ---------------- final linear ----------------
__global__ __launch_bounds__(256) void final_k(
    const float* __restrict__ hfinal, const float* __restrict__ gp,
    const float* __restrict__ fW, const float* __restrict__ fb,
    float* __restrict__ out)
{
    int tid = threadIdx.x;
    int w = tid >> 6, l = tid & 63;
    int b = blockIdx.x * 4 + w;
    const float* hf = hfinal + (size_t)(0 * 512 + b) * 128;
    const float* hb = hfinal + (size_t)(1 * 512 + b) * 128;
    float s = hf[l] * fW[l] + hf[l + 64] * fW[l + 64]
            + hb[l] * fW[128 + l] + hb[l + 64] * fW[192 + l];
    if (l < 8) s += gp[b * 8 + l] * fW[256 + l];
    #pragma unroll
    for (int off = 32; off > 0; off >>= 1) s += __shfl_down(s, off);
    if (l == 0) out[b] = s + fb[0];
}

// ---------------- launcher ----------------
extern "C" void kernel_launch(void* const* d_in, const int* in_sizes, int n_in,
                              void* d_out, int out_size, void* d_ws, size_t ws_size,
                              hipStream_t stream)
{
    const int*   tokens        = (const int*)  d_in[0];
    const int*   token_lens    = (const int*)  d_in[1];
    const int*   block_lens    = (const int*)  d_in[2];
    const float* instr_params  = (const float*)d_in[3];
    const float* global_params = (const float*)d_in[4];
    const float* emb           = (const float*)d_in[5];
    const float* cWihF = (const float*)d_in[6];
    const float* cWhhF = (const float*)d_in[7];
    const float* cbF   = (const float*)d_in[8];
    const float* cWihB = (const float*)d_in[9];
    const float* cWhhB = (const float*)d_in[10];
    const float* cbB   = (const float*)d_in[11];
    const float* wWihF = (const float*)d_in[12];
    const float* wWhhF = (const float*)d_in[13];
    const float* wbF   = (const float*)d_in[14];
    const float* wWihB = (const float*)d_in[15];
    const float* wWhhB = (const float*)d_in[16];
    const float* wbB   = (const float*)d_in[17];
    const float* fW    = (const float*)d_in[18];
    const float* fb    = (const float*)d_in[19];
    float* out = (float*)d_out;

    char* ws = (char*)d_ws;
    size_t off = 0;
    auto alloc_f = [&](size_t nfloats) { float* p = (float*)(ws + off); off += nfloats * 4; return p; };

    float* W4cf    = alloc_f(131072);
    float* W4cb    = alloc_f(131072);
    float* W4p     = alloc_f(303104);
    float* W4h     = alloc_f(131072);
    float* instr_h = alloc_f((size_t)N_INSTR * 256);
    float* xw      = alloc_f((size_t)N_INSTR * 296);
    float* P       = alloc_f((size_t)N_INSTR * 1024);
    float* hfin    = alloc_f(2 * 512 * 128);        // final word h, (dir, block) layout
    float* EF4     = alloc_f((size_t)N_TOKENS * 128 * 4);
    float* EB4     = alloc_f((size_t)N_TOKENS * 128 * 4);
    int*   starts  = (int*)(ws + off); off += 512 * 4;
    int*   bid     = (int*)(ws + off); off += N_INSTR * 4;
    int*   order   = (int*)(ws + off); off += N_INSTR * 4;
    int*   border  = (int*)(ws + off); off += 512 * 4;

    prep_pack<<<2720, 256, 0, stream>>>(cWihF, cWhhF, cWihB, cWhhB,
                                        wWihF, wWihB, wWhhF, wWhhB,
                                        W4cf, W4cb, W4p, W4h);
    scan_kernel<<<1, 512, 0, stream>>>(block_lens, starts, bid);
    sort_by_len<<<1, 256, 0, stream>>>(token_lens, order);
    sort_blocks<<<1, 512, 0, stream>>>(block_lens, border);
    ex_pack<<<N_TOKENS, 256, 0, stream>>>(emb, W4cf, W4cb, EF4, EB4);

    char_lstm<<<N_INSTR / CIB, 256, 0, stream>>>(tokens, token_lens, order,
                                                 EF4, EB4, W4cf, W4cb,
                                                 cbF, cbB, instr_h);
    xw_gather<<<4736, 256, 0, stream>>>(instr_h, instr_params, global_params, bid, xw);
    word_proj<<<4096, 256, 0, stream>>>(xw, W4p, wbF, wbB, P);
    word_lstm<<<256, 256, 0, stream>>>(W4h, P, starts, block_lens, border, hfin);
    final_k<<<128, 256, 0, stream>>>(hfin, global_params, fW, fb, out);
}